// Round 1
// baseline (207.671 us; speedup 1.0000x reference)
//
#include <hip/hip_runtime.h>

namespace {
constexpr int Gc = 64, Lc = 256, Kc = 32, Nc = Gc * Lc, HIDc = 32, NBc = 10;
constexpr float C_S = 0.3826834323650898f;   // sin(pi/8)
constexpr float C_X = 0.9238795325112867f;   // cos(pi/8)
constexpr float SQ3 = 1.7320508075688772f;
constexpr float INV_SQRT_K   = 0.17677669529663687f;  // 1/sqrt(32)
constexpr float INV_SQRT_HID = 0.17677669529663687f;  // 1/sqrt(32)
constexpr float INV_SQRT_NB  = 0.31622776601683794f;  // 1/sqrt(10)
constexpr float INV_SQRT_2HID = 0.125f;               // 1/sqrt(64)
constexpr float INV_STEP  = 1.8f;                     // 1/(5/9)
constexpr float EMB_SCALE = 0.8928571428571429f;      // 1/1.12

__device__ __forceinline__ float silu_f(float x) {
    return x / (1.0f + __expf(-x));
}
} // namespace

// Phase 1: per edge, radial MLP #1 -> per-node segment sums (32-lane butterfly)
// -> node-level h_s/h_v, sc_v, s1, v1 -> write per-node float4 table
// tab[n][u] = (s1[u]*c2a[u], v1[u][0..2]*c2b[u]) and C_S*sc_v into out.
__global__ __launch_bounds__(256) void se3_phase1(
    const float* __restrict__ coords, const float* __restrict__ t,
    const int* __restrict__ batch, const int* __restrict__ esrc,
    const float* __restrict__ emask,
    const float* __restrict__ sc1_w, const float* __restrict__ lin1_w,
    const float* __restrict__ W0, const float* __restrict__ W1,
    const float* __restrict__ W2,
    const float* __restrict__ l2s, const float* __restrict__ l2v,
    const float* __restrict__ sc2_w, const float* __restrict__ lin1s,
    const float* __restrict__ lin1v,
    const float* __restrict__ c2a, const float* __restrict__ c2b,
    float4* __restrict__ tab, float* __restrict__ out_scpart)
{
    const int e    = blockIdx.x * 256 + threadIdx.x;
    const int n    = e >> 5;            // edge_dst is repeat(arange(N), K)
    const int u    = threadIdx.x & 31;  // lane within the node's 32-edge group
    const int src  = esrc[e];
    const float em = emask[e];

    const float dx = coords[3 * n + 0] - coords[3 * src + 0];
    const float dy = coords[3 * n + 1] - coords[3 * src + 1];
    const float dz = coords[3 * n + 2] - coords[3 * src + 2];
    const float r  = sqrtf(dx * dx + dy * dy + dz * dz + 1e-12f);
    const float ir = 1.0f / r;
    const float shx = SQ3 * dx * ir, shy = SQ3 * dy * ir, shz = SQ3 * dz * ir;

    float emb[NBc];
#pragma unroll
    for (int b = 0; b < NBc; ++b) {
        const float d = r * INV_STEP - (float)b;
        emb[b] = __expf(-d * d) * EMB_SCALE;
    }

    float h1[HIDc];
#pragma unroll
    for (int j = 0; j < HIDc; ++j) {
        float acc = 0.f;
#pragma unroll
        for (int b = 0; b < NBc; ++b) acc = fmaf(emb[b], W0[b * HIDc + j], acc);
        h1[j] = silu_f(acc * INV_SQRT_NB);
    }

    float h2[HIDc];
#pragma unroll
    for (int j = 0; j < HIDc; ++j) {
        float acc = 0.f;
#pragma unroll
        for (int v = 0; v < HIDc; ++v) acc = fmaf(h1[v], W1[v * HIDc + j], acc);
        h2[j] = silu_f(acc * INV_SQRT_HID);
    }

    float w10 = 0.f, w11 = 0.f;
#pragma unroll
    for (int v = 0; v < HIDc; ++v) {
        w10 = fmaf(h2[v], W2[2 * v + 0], w10);
        w11 = fmaf(h2[v], W2[2 * v + 1], w11);
    }
    w10 *= INV_SQRT_HID;
    w11 *= INV_SQRT_HID;

    const float xs = t[batch[src]] * lin1_w[0];
    float ms = w10 * xs * em;
    const float fv = w11 * xs * em;
    float mvx = fv * shx, mvy = fv * shy, mvz = fv * shz;

#pragma unroll
    for (int m = 16; m >= 1; m >>= 1) {
        ms  += __shfl_xor(ms,  m, 32);
        mvx += __shfl_xor(mvx, m, 32);
        mvy += __shfl_xor(mvy, m, 32);
        mvz += __shfl_xor(mvz, m, 32);
    }
    const float nms = ms  * INV_SQRT_K;
    const float nvx = mvx * INV_SQRT_K;
    const float nvy = mvy * INV_SQRT_K;
    const float nvz = mvz * INV_SQRT_K;

    // ---- node phase: this lane now owns hidden unit u of node n ----
    const float a  = t[batch[n]];
    const float hs = silu_f(C_S * a * sc1_w[u] + C_X * nms * a * l2s[u]);
    const float lv = l2v[u];
    const float hvx = silu_f(C_X * nvx * a * lv);
    const float hvy = silu_f(C_X * nvy * a * lv);
    const float hvz = silu_f(C_X * nvz * a * lv);

    const float s2 = sc2_w[u];
    float scx = hvx * s2, scy = hvy * s2, scz = hvz * s2;
#pragma unroll
    for (int m = 16; m >= 1; m >>= 1) {
        scx += __shfl_xor(scx, m, 32);
        scy += __shfl_xor(scy, m, 32);
        scz += __shfl_xor(scz, m, 32);
    }

    float s1 = 0.f, v1x = 0.f, v1y = 0.f, v1z = 0.f;
    for (int v = 0; v < HIDc; ++v) {
        const float hsv = __shfl(hs,  v, 32);
        const float hx  = __shfl(hvx, v, 32);
        const float hy  = __shfl(hvy, v, 32);
        const float hz  = __shfl(hvz, v, 32);
        const float wsv = lin1s[v * HIDc + u];
        const float wvv = lin1v[v * HIDc + u];
        s1  = fmaf(hsv, wsv, s1);
        v1x = fmaf(hx, wvv, v1x);
        v1y = fmaf(hy, wvv, v1y);
        v1z = fmaf(hz, wvv, v1z);
    }
    const float sa = INV_SQRT_HID * a;
    float4 o;
    o.x = s1  * sa * c2a[u];
    o.y = v1x * sa * c2b[u];
    o.z = v1y * sa * c2b[u];
    o.w = v1z * sa * c2b[u];
    tab[n * HIDc + u] = o;

    if (u == 0) {
        const float s = C_S * a * INV_SQRT_HID;
        out_scpart[3 * n + 0] = scx * s;
        out_scpart[3 * n + 1] = scy * s;
        out_scpart[3 * n + 2] = scz * s;
    }
}

// Phase 2: per edge, radial MLP #2, fold conv2_l2a/l2b contraction into the
// edge loop (p, q[3] scalars), 32-lane butterfly segment-sum, lane0 RMW out.
__global__ __launch_bounds__(256) void se3_phase2(
    const float* __restrict__ coords, const float* __restrict__ t,
    const int* __restrict__ batch, const int* __restrict__ esrc,
    const float* __restrict__ emask,
    const float* __restrict__ W0, const float* __restrict__ W1,
    const float* __restrict__ W2,
    const float4* __restrict__ tab, float* __restrict__ out)
{
    const int e    = blockIdx.x * 256 + threadIdx.x;
    const int n    = e >> 5;
    const int lane = threadIdx.x & 31;
    const int src  = esrc[e];
    const float em = emask[e];

    const float dx = coords[3 * n + 0] - coords[3 * src + 0];
    const float dy = coords[3 * n + 1] - coords[3 * src + 1];
    const float dz = coords[3 * n + 2] - coords[3 * src + 2];
    const float r  = sqrtf(dx * dx + dy * dy + dz * dz + 1e-12f);
    const float ir = 1.0f / r;
    const float shx = SQ3 * dx * ir, shy = SQ3 * dy * ir, shz = SQ3 * dz * ir;

    float emb[NBc];
#pragma unroll
    for (int b = 0; b < NBc; ++b) {
        const float d = r * INV_STEP - (float)b;
        emb[b] = __expf(-d * d) * EMB_SCALE;
    }

    float h1[HIDc];
#pragma unroll
    for (int j = 0; j < HIDc; ++j) {
        float acc = 0.f;
#pragma unroll
        for (int b = 0; b < NBc; ++b) acc = fmaf(emb[b], W0[b * HIDc + j], acc);
        h1[j] = silu_f(acc * INV_SQRT_NB);
    }

    float h2[HIDc];
#pragma unroll
    for (int j = 0; j < HIDc; ++j) {
        float acc = 0.f;
#pragma unroll
        for (int v = 0; v < HIDc; ++v) acc = fmaf(h1[v], W1[v * HIDc + j], acc);
        h2[j] = silu_f(acc * INV_SQRT_HID);
    }

    float p = 0.f, qx = 0.f, qy = 0.f, qz = 0.f;
#pragma unroll
    for (int j = 0; j < HIDc; ++j) {
        float wa = 0.f, wb = 0.f;
#pragma unroll
        for (int v = 0; v < HIDc; ++v) {
            wa = fmaf(h2[v], W2[v * 64 + j],      wa);
            wb = fmaf(h2[v], W2[v * 64 + 32 + j], wb);
        }
        const float4 tb = tab[src * HIDc + j];
        p  = fmaf(wa, tb.x, p);
        qx = fmaf(wb, tb.y, qx);
        qy = fmaf(wb, tb.z, qy);
        qz = fmaf(wb, tb.w, qz);
    }
    p  *= INV_SQRT_HID;
    qx *= INV_SQRT_HID;
    qy *= INV_SQRT_HID;
    qz *= INV_SQRT_HID;

    float cx = em * fmaf(p, shx, qx);
    float cy = em * fmaf(p, shy, qy);
    float cz = em * fmaf(p, shz, qz);
#pragma unroll
    for (int m = 16; m >= 1; m >>= 1) {
        cx += __shfl_xor(cx, m, 32);
        cy += __shfl_xor(cy, m, 32);
        cz += __shfl_xor(cz, m, 32);
    }

    if (lane == 0) {
        const float a = t[batch[n]];
        const float s = C_X * a * INV_SQRT_2HID * INV_SQRT_K;
        out[3 * n + 0] = out[3 * n + 0] + cx * s;
        out[3 * n + 1] = out[3 * n + 1] + cy * s;
        out[3 * n + 2] = out[3 * n + 2] + cz * s;
    }
}

extern "C" void kernel_launch(void* const* d_in, const int* in_sizes, int n_in,
                              void* d_out, int out_size, void* d_ws, size_t ws_size,
                              hipStream_t stream) {
    const float* coords = (const float*)d_in[0];
    const float* t      = (const float*)d_in[1];
    const int*   batch  = (const int*)d_in[2];
    const int*   esrc   = (const int*)d_in[3];
    // d_in[4] = edge_dst (implicit: e>>5), unused
    const float* emask  = (const float*)d_in[5];
    const float* sc1_w  = (const float*)d_in[6];
    const float* lin1_w = (const float*)d_in[7];
    const float* fc1_w0 = (const float*)d_in[8];
    const float* fc1_w1 = (const float*)d_in[9];
    const float* fc1_w2 = (const float*)d_in[10];
    const float* c1l2s  = (const float*)d_in[11];
    const float* c1l2v  = (const float*)d_in[12];
    const float* sc2_w  = (const float*)d_in[13];
    const float* lin1s  = (const float*)d_in[14];
    const float* lin1v  = (const float*)d_in[15];
    const float* fc2_w0 = (const float*)d_in[16];
    const float* fc2_w1 = (const float*)d_in[17];
    const float* fc2_w2 = (const float*)d_in[18];
    const float* c2a    = (const float*)d_in[19];
    const float* c2b    = (const float*)d_in[20];

    float*  out = (float*)d_out;
    float4* tab = (float4*)d_ws;   // N*HID float4 = 8 MB

    const int nEdges = Nc * Kc;            // 524288
    dim3 block(256);
    dim3 grid(nEdges / 256);               // 2048 blocks

    se3_phase1<<<grid, block, 0, stream>>>(coords, t, batch, esrc, emask,
        sc1_w, lin1_w, fc1_w0, fc1_w1, fc1_w2, c1l2s, c1l2v, sc2_w,
        lin1s, lin1v, c2a, c2b, tab, out);

    se3_phase2<<<grid, block, 0, stream>>>(coords, t, batch, esrc, emask,
        fc2_w0, fc2_w1, fc2_w2, tab, out);
}

// Round 2
// 179.066 us; speedup vs baseline: 1.1597x; 1.1597x over previous
//
#include <hip/hip_runtime.h>

namespace {
constexpr int Gc = 64, Lc = 256, Kc = 32, Nc = Gc * Lc, HIDc = 32, NBc = 10;
constexpr float C_S = 0.3826834323650898f;   // sin(pi/8)
constexpr float C_X = 0.9238795325112867f;   // cos(pi/8)
constexpr float SQ3 = 1.7320508075688772f;
constexpr float INV_SQRT_K   = 0.17677669529663687f;  // 1/sqrt(32)
constexpr float INV_SQRT_HID = 0.17677669529663687f;  // 1/sqrt(32)
constexpr float INV_SQRT_NB  = 0.31622776601683794f;  // 1/sqrt(10)
constexpr float INV_SQRT_2HID = 0.125f;               // 1/sqrt(64)
constexpr float INV_STEP  = 1.8f;                     // 1/(5/9)
constexpr float EMB_SCALE = 0.8928571428571429f;      // 1/1.12

__device__ __forceinline__ float silu_f(float x) {
    return x / (1.0f + __expf(-x));
}
} // namespace

// Phase 1: per edge, radial MLP #1 -> 32-lane butterfly segment sums ->
// node-level h_s/h_v, sc_v, s1, v1. Epilogue: contract fc2_w2 against the
// per-node o-vector NOW (amortized over the node's K=32 edges) so phase2
// only needs a 32 x float4 dot with h2:
//   tab2[n][v] = ( Sum_j W2a[v][j]*o.x[j],  Sum_j W2b[v][j]*o.{y,z,w}[j] ) / sqrt(HID)
__global__ __launch_bounds__(256) void se3_phase1(
    const float* __restrict__ coords, const float* __restrict__ t,
    const int* __restrict__ batch, const int* __restrict__ esrc,
    const float* __restrict__ emask,
    const float* __restrict__ sc1_w, const float* __restrict__ lin1_w,
    const float* __restrict__ W0, const float* __restrict__ W1,
    const float* __restrict__ W2,
    const float* __restrict__ l2s, const float* __restrict__ l2v,
    const float* __restrict__ sc2_w, const float* __restrict__ lin1s,
    const float* __restrict__ lin1v,
    const float* __restrict__ c2a, const float* __restrict__ c2b,
    const float* __restrict__ W2f2,          // fc2_w2 (HID x 2*HID)
    float4* __restrict__ tab2, float* __restrict__ out_scpart)
{
    const int e    = blockIdx.x * 256 + threadIdx.x;
    const int n    = e >> 5;            // edge_dst is repeat(arange(N), K)
    const int u    = threadIdx.x & 31;  // lane within the node's 32-edge group
    const int src  = esrc[e];
    const float em = emask[e];

    const float dx = coords[3 * n + 0] - coords[3 * src + 0];
    const float dy = coords[3 * n + 1] - coords[3 * src + 1];
    const float dz = coords[3 * n + 2] - coords[3 * src + 2];
    const float r  = sqrtf(dx * dx + dy * dy + dz * dz + 1e-12f);
    const float ir = 1.0f / r;
    const float shx = SQ3 * dx * ir, shy = SQ3 * dy * ir, shz = SQ3 * dz * ir;

    float emb[NBc];
#pragma unroll
    for (int b = 0; b < NBc; ++b) {
        const float d = r * INV_STEP - (float)b;
        emb[b] = __expf(-d * d) * EMB_SCALE;
    }

    float h1[HIDc];
#pragma unroll
    for (int j = 0; j < HIDc; ++j) {
        float acc = 0.f;
#pragma unroll
        for (int b = 0; b < NBc; ++b) acc = fmaf(emb[b], W0[b * HIDc + j], acc);
        h1[j] = silu_f(acc * INV_SQRT_NB);
    }

    float h2[HIDc];
#pragma unroll
    for (int j = 0; j < HIDc; ++j) {
        float acc = 0.f;
#pragma unroll
        for (int v = 0; v < HIDc; ++v) acc = fmaf(h1[v], W1[v * HIDc + j], acc);
        h2[j] = silu_f(acc * INV_SQRT_HID);
    }

    float w10 = 0.f, w11 = 0.f;
#pragma unroll
    for (int v = 0; v < HIDc; ++v) {
        w10 = fmaf(h2[v], W2[2 * v + 0], w10);
        w11 = fmaf(h2[v], W2[2 * v + 1], w11);
    }
    w10 *= INV_SQRT_HID;
    w11 *= INV_SQRT_HID;

    const float xs = t[batch[src]] * lin1_w[0];
    float ms = w10 * xs * em;
    const float fv = w11 * xs * em;
    float mvx = fv * shx, mvy = fv * shy, mvz = fv * shz;

#pragma unroll
    for (int m = 16; m >= 1; m >>= 1) {
        ms  += __shfl_xor(ms,  m, 32);
        mvx += __shfl_xor(mvx, m, 32);
        mvy += __shfl_xor(mvy, m, 32);
        mvz += __shfl_xor(mvz, m, 32);
    }
    const float nms = ms  * INV_SQRT_K;
    const float nvx = mvx * INV_SQRT_K;
    const float nvy = mvy * INV_SQRT_K;
    const float nvz = mvz * INV_SQRT_K;

    // ---- node phase: this lane now owns hidden unit u of node n ----
    const float a  = t[batch[n]];
    const float hs = silu_f(C_S * a * sc1_w[u] + C_X * nms * a * l2s[u]);
    const float lv = l2v[u];
    const float hvx = silu_f(C_X * nvx * a * lv);
    const float hvy = silu_f(C_X * nvy * a * lv);
    const float hvz = silu_f(C_X * nvz * a * lv);

    const float s2 = sc2_w[u];
    float scx = hvx * s2, scy = hvy * s2, scz = hvz * s2;
#pragma unroll
    for (int m = 16; m >= 1; m >>= 1) {
        scx += __shfl_xor(scx, m, 32);
        scy += __shfl_xor(scy, m, 32);
        scz += __shfl_xor(scz, m, 32);
    }

    float s1 = 0.f, v1x = 0.f, v1y = 0.f, v1z = 0.f;
    for (int v = 0; v < HIDc; ++v) {
        const float hsv = __shfl(hs,  v, 32);
        const float hx  = __shfl(hvx, v, 32);
        const float hy  = __shfl(hvy, v, 32);
        const float hz  = __shfl(hvz, v, 32);
        const float wsv = lin1s[v * HIDc + u];
        const float wvv = lin1v[v * HIDc + u];
        s1  = fmaf(hsv, wsv, s1);
        v1x = fmaf(hx, wvv, v1x);
        v1y = fmaf(hy, wvv, v1y);
        v1z = fmaf(hz, wvv, v1z);
    }
    const float sa = INV_SQRT_HID * a;
    const float ox_ = s1  * sa * c2a[u];
    const float oy_ = v1x * sa * c2b[u];
    const float oz_ = v1y * sa * c2b[u];
    const float ow_ = v1z * sa * c2b[u];

    // ---- epilogue: fold fc2_w2 contraction into a per-node table ----
    // lane u computes row v=u of A/B:  weights W2f2[u*64 + j] (contiguous).
    float A = 0.f, Bx = 0.f, By = 0.f, Bz = 0.f;
#pragma unroll
    for (int j = 0; j < HIDc; ++j) {
        const float ojx = __shfl(ox_, j, 32);
        const float ojy = __shfl(oy_, j, 32);
        const float ojz = __shfl(oz_, j, 32);
        const float ojw = __shfl(ow_, j, 32);
        const float wa  = W2f2[u * 64 + j];
        const float wb  = W2f2[u * 64 + 32 + j];
        A  = fmaf(wa, ojx, A);
        Bx = fmaf(wb, ojy, Bx);
        By = fmaf(wb, ojz, By);
        Bz = fmaf(wb, ojw, Bz);
    }
    float4 t2;
    t2.x = A  * INV_SQRT_HID;   // fold _radial's final /sqrt(HID) here
    t2.y = Bx * INV_SQRT_HID;
    t2.z = By * INV_SQRT_HID;
    t2.w = Bz * INV_SQRT_HID;
    tab2[n * HIDc + u] = t2;

    if (u == 0) {
        const float s = C_S * a * INV_SQRT_HID;
        out_scpart[3 * n + 0] = scx * s;
        out_scpart[3 * n + 1] = scy * s;
        out_scpart[3 * n + 2] = scz * s;
    }
}

// Phase 2: per edge, radial MLP #2 up to h2 only; then p/q are a single
// 32 x float4 dot with tab2[src] (W2 contraction already baked in).
__global__ __launch_bounds__(256) void se3_phase2(
    const float* __restrict__ coords, const float* __restrict__ t,
    const int* __restrict__ batch, const int* __restrict__ esrc,
    const float* __restrict__ emask,
    const float* __restrict__ W0, const float* __restrict__ W1,
    const float4* __restrict__ tab2, float* __restrict__ out)
{
    const int e    = blockIdx.x * 256 + threadIdx.x;
    const int n    = e >> 5;
    const int lane = threadIdx.x & 31;
    const int src  = esrc[e];
    const float em = emask[e];

    const float dx = coords[3 * n + 0] - coords[3 * src + 0];
    const float dy = coords[3 * n + 1] - coords[3 * src + 1];
    const float dz = coords[3 * n + 2] - coords[3 * src + 2];
    const float r  = sqrtf(dx * dx + dy * dy + dz * dz + 1e-12f);
    const float ir = 1.0f / r;
    const float shx = SQ3 * dx * ir, shy = SQ3 * dy * ir, shz = SQ3 * dz * ir;

    float emb[NBc];
#pragma unroll
    for (int b = 0; b < NBc; ++b) {
        const float d = r * INV_STEP - (float)b;
        emb[b] = __expf(-d * d) * EMB_SCALE;
    }

    float h1[HIDc];
#pragma unroll
    for (int j = 0; j < HIDc; ++j) {
        float acc = 0.f;
#pragma unroll
        for (int b = 0; b < NBc; ++b) acc = fmaf(emb[b], W0[b * HIDc + j], acc);
        h1[j] = silu_f(acc * INV_SQRT_NB);
    }

    float h2[HIDc];
#pragma unroll
    for (int j = 0; j < HIDc; ++j) {
        float acc = 0.f;
#pragma unroll
        for (int v = 0; v < HIDc; ++v) acc = fmaf(h1[v], W1[v * HIDc + j], acc);
        h2[j] = silu_f(acc * INV_SQRT_HID);
    }

    float p = 0.f, qx = 0.f, qy = 0.f, qz = 0.f;
    const float4* __restrict__ tsrc = tab2 + src * HIDc;
#pragma unroll
    for (int v = 0; v < HIDc; ++v) {
        const float4 tv = tsrc[v];
        p  = fmaf(h2[v], tv.x, p);
        qx = fmaf(h2[v], tv.y, qx);
        qy = fmaf(h2[v], tv.z, qy);
        qz = fmaf(h2[v], tv.w, qz);
    }

    float cx = em * fmaf(p, shx, qx);
    float cy = em * fmaf(p, shy, qy);
    float cz = em * fmaf(p, shz, qz);
#pragma unroll
    for (int m = 16; m >= 1; m >>= 1) {
        cx += __shfl_xor(cx, m, 32);
        cy += __shfl_xor(cy, m, 32);
        cz += __shfl_xor(cz, m, 32);
    }

    if (lane == 0) {
        const float a = t[batch[n]];
        const float s = C_X * a * INV_SQRT_2HID * INV_SQRT_K;
        out[3 * n + 0] = out[3 * n + 0] + cx * s;
        out[3 * n + 1] = out[3 * n + 1] + cy * s;
        out[3 * n + 2] = out[3 * n + 2] + cz * s;
    }
}

extern "C" void kernel_launch(void* const* d_in, const int* in_sizes, int n_in,
                              void* d_out, int out_size, void* d_ws, size_t ws_size,
                              hipStream_t stream) {
    const float* coords = (const float*)d_in[0];
    const float* t      = (const float*)d_in[1];
    const int*   batch  = (const int*)d_in[2];
    const int*   esrc   = (const int*)d_in[3];
    // d_in[4] = edge_dst (implicit: e>>5), unused
    const float* emask  = (const float*)d_in[5];
    const float* sc1_w  = (const float*)d_in[6];
    const float* lin1_w = (const float*)d_in[7];
    const float* fc1_w0 = (const float*)d_in[8];
    const float* fc1_w1 = (const float*)d_in[9];
    const float* fc1_w2 = (const float*)d_in[10];
    const float* c1l2s  = (const float*)d_in[11];
    const float* c1l2v  = (const float*)d_in[12];
    const float* sc2_w  = (const float*)d_in[13];
    const float* lin1s  = (const float*)d_in[14];
    const float* lin1v  = (const float*)d_in[15];
    const float* fc2_w0 = (const float*)d_in[16];
    const float* fc2_w1 = (const float*)d_in[17];
    const float* fc2_w2 = (const float*)d_in[18];
    const float* c2a    = (const float*)d_in[19];
    const float* c2b    = (const float*)d_in[20];

    float*  out  = (float*)d_out;
    float4* tab2 = (float4*)d_ws;   // N*HID float4 = 8 MB

    const int nEdges = Nc * Kc;            // 524288
    dim3 block(256);
    dim3 grid(nEdges / 256);               // 2048 blocks

    se3_phase1<<<grid, block, 0, stream>>>(coords, t, batch, esrc, emask,
        sc1_w, lin1_w, fc1_w0, fc1_w1, fc1_w2, c1l2s, c1l2v, sc2_w,
        lin1s, lin1v, c2a, c2b, fc2_w2, tab2, out);

    se3_phase2<<<grid, block, 0, stream>>>(coords, t, batch, esrc, emask,
        fc2_w0, fc2_w1, tab2, out);
}

// Round 5
// 162.526 us; speedup vs baseline: 1.2778x; 1.1018x over previous
//
#include <hip/hip_runtime.h>

namespace {
constexpr int Kc = 32, HIDc = 32, NBc = 10;
constexpr float C_S = 0.3826834323650898f;   // sin(pi/8)
constexpr float C_X = 0.9238795325112867f;   // cos(pi/8)
constexpr float SQ3 = 1.7320508075688772f;
constexpr float INV_SQRT_K   = 0.17677669529663687f;  // 1/sqrt(32)
constexpr float INV_SQRT_HID = 0.17677669529663687f;  // 1/sqrt(32)
constexpr float INV_SQRT_NB  = 0.31622776601683794f;  // 1/sqrt(10)
constexpr float INV_SQRT_2HID = 0.125f;               // 1/sqrt(64)
constexpr float INV_STEP  = 1.8f;                     // 1/(5/9)
constexpr float EMB_SCALE = 0.8928571428571429f;      // 1/1.12

typedef __attribute__((ext_vector_type(8)))  short bf16x8;
typedef __attribute__((ext_vector_type(16))) float f32x16;
typedef __attribute__((ext_vector_type(4)))  int   i32x4;

__device__ __forceinline__ float silu_div(float x) {
    return x / (1.0f + __expf(-x));
}
__device__ __forceinline__ float silu_rcp(float x) {
    return x * __builtin_amdgcn_rcpf(1.0f + __expf(-x));
}

// pack two f32 into one VGPR as 2 bf16 (truncation): low16=bf16(a), high16=bf16(b)
__device__ __forceinline__ unsigned pk_hi(float a, float b) {
    unsigned ua = __builtin_bit_cast(unsigned, a);
    unsigned ub = __builtin_bit_cast(unsigned, b);
    return (ua >> 16) | (ub & 0xFFFF0000u);
}
__device__ __forceinline__ float trunc_hi(float a) {
    return __builtin_bit_cast(float, __builtin_bit_cast(unsigned, a) & 0xFFFF0000u);
}
__device__ __forceinline__ bf16x8 mk_frag(unsigned r0, unsigned r1, unsigned r2, unsigned r3) {
    i32x4 t; t[0] = (int)r0; t[1] = (int)r1; t[2] = (int)r2; t[3] = (int)r3;
    return __builtin_bit_cast(bf16x8, t);
}
__device__ __forceinline__ f32x16 mfma32(bf16x8 a, bf16x8 b, f32x16 c) {
    return __builtin_amdgcn_mfma_f32_32x32x16_bf16(a, b, c, 0, 0, 0);
}
} // namespace

// ---------------------------------------------------------------------------
// Phase 1 — EXACT copy of the R2 kernel that passed (all risk isolated to
// phase2 this round). Radial MLP #1 -> butterfly segment sums -> node
// h_s/h_v -> sc_v part of out; epilogue folds fc2_w2 into tab2.
// ---------------------------------------------------------------------------
__global__ __launch_bounds__(256) void se3_phase1(
    const float* __restrict__ coords, const float* __restrict__ t,
    const int* __restrict__ batch, const int* __restrict__ esrc,
    const float* __restrict__ emask,
    const float* __restrict__ sc1_w, const float* __restrict__ lin1_w,
    const float* __restrict__ W0, const float* __restrict__ W1,
    const float* __restrict__ W2,
    const float* __restrict__ l2s, const float* __restrict__ l2v,
    const float* __restrict__ sc2_w, const float* __restrict__ lin1s,
    const float* __restrict__ lin1v,
    const float* __restrict__ c2a, const float* __restrict__ c2b,
    const float* __restrict__ W2f2,
    float4* __restrict__ tab2, float* __restrict__ out_scpart)
{
    const int e    = blockIdx.x * 256 + threadIdx.x;
    const int n    = e >> 5;            // edge_dst = repeat(arange(N), K)
    const int u    = threadIdx.x & 31;
    const int src  = esrc[e];
    const float em = emask[e];

    const float dx = coords[3 * n + 0] - coords[3 * src + 0];
    const float dy = coords[3 * n + 1] - coords[3 * src + 1];
    const float dz = coords[3 * n + 2] - coords[3 * src + 2];
    const float r  = sqrtf(dx * dx + dy * dy + dz * dz + 1e-12f);
    const float ir = 1.0f / r;
    const float shx = SQ3 * dx * ir, shy = SQ3 * dy * ir, shz = SQ3 * dz * ir;

    float emb[NBc];
#pragma unroll
    for (int b = 0; b < NBc; ++b) {
        const float d = r * INV_STEP - (float)b;
        emb[b] = __expf(-d * d) * EMB_SCALE;
    }

    float h1[HIDc];
#pragma unroll
    for (int j = 0; j < HIDc; ++j) {
        float acc = 0.f;
#pragma unroll
        for (int b = 0; b < NBc; ++b) acc = fmaf(emb[b], W0[b * HIDc + j], acc);
        h1[j] = silu_div(acc * INV_SQRT_NB);
    }

    float h2[HIDc];
#pragma unroll
    for (int j = 0; j < HIDc; ++j) {
        float acc = 0.f;
#pragma unroll
        for (int v = 0; v < HIDc; ++v) acc = fmaf(h1[v], W1[v * HIDc + j], acc);
        h2[j] = silu_div(acc * INV_SQRT_HID);
    }

    float w10 = 0.f, w11 = 0.f;
#pragma unroll
    for (int v = 0; v < HIDc; ++v) {
        w10 = fmaf(h2[v], W2[2 * v + 0], w10);
        w11 = fmaf(h2[v], W2[2 * v + 1], w11);
    }
    w10 *= INV_SQRT_HID;
    w11 *= INV_SQRT_HID;

    const float xs = t[batch[src]] * lin1_w[0];
    float ms = w10 * xs * em;
    const float fv = w11 * xs * em;
    float mvx = fv * shx, mvy = fv * shy, mvz = fv * shz;

#pragma unroll
    for (int m = 16; m >= 1; m >>= 1) {
        ms  += __shfl_xor(ms,  m, 32);
        mvx += __shfl_xor(mvx, m, 32);
        mvy += __shfl_xor(mvy, m, 32);
        mvz += __shfl_xor(mvz, m, 32);
    }
    const float nms = ms  * INV_SQRT_K;
    const float nvx = mvx * INV_SQRT_K;
    const float nvy = mvy * INV_SQRT_K;
    const float nvz = mvz * INV_SQRT_K;

    const float a  = t[batch[n]];
    const float hs = silu_div(C_S * a * sc1_w[u] + C_X * nms * a * l2s[u]);
    const float lv = l2v[u];
    const float hvx = silu_div(C_X * nvx * a * lv);
    const float hvy = silu_div(C_X * nvy * a * lv);
    const float hvz = silu_div(C_X * nvz * a * lv);

    const float s2 = sc2_w[u];
    float scx = hvx * s2, scy = hvy * s2, scz = hvz * s2;
#pragma unroll
    for (int m = 16; m >= 1; m >>= 1) {
        scx += __shfl_xor(scx, m, 32);
        scy += __shfl_xor(scy, m, 32);
        scz += __shfl_xor(scz, m, 32);
    }

    float s1 = 0.f, v1x = 0.f, v1y = 0.f, v1z = 0.f;
    for (int v = 0; v < HIDc; ++v) {
        const float hsv = __shfl(hs,  v, 32);
        const float hx  = __shfl(hvx, v, 32);
        const float hy  = __shfl(hvy, v, 32);
        const float hz  = __shfl(hvz, v, 32);
        const float wsv = lin1s[v * HIDc + u];
        const float wvv = lin1v[v * HIDc + u];
        s1  = fmaf(hsv, wsv, s1);
        v1x = fmaf(hx, wvv, v1x);
        v1y = fmaf(hy, wvv, v1y);
        v1z = fmaf(hz, wvv, v1z);
    }
    const float sa = INV_SQRT_HID * a;
    const float ox_ = s1  * sa * c2a[u];
    const float oy_ = v1x * sa * c2b[u];
    const float oz_ = v1y * sa * c2b[u];
    const float ow_ = v1z * sa * c2b[u];

    float A = 0.f, Bx = 0.f, By = 0.f, Bz = 0.f;
#pragma unroll
    for (int j = 0; j < HIDc; ++j) {
        const float ojx = __shfl(ox_, j, 32);
        const float ojy = __shfl(oy_, j, 32);
        const float ojz = __shfl(oz_, j, 32);
        const float ojw = __shfl(ow_, j, 32);
        const float wa  = W2f2[u * 64 + j];
        const float wb  = W2f2[u * 64 + 32 + j];
        A  = fmaf(wa, ojx, A);
        Bx = fmaf(wb, ojy, Bx);
        By = fmaf(wb, ojz, By);
        Bz = fmaf(wb, ojw, Bz);
    }
    float4 t2;
    t2.x = A  * INV_SQRT_HID;
    t2.y = Bx * INV_SQRT_HID;
    t2.z = By * INV_SQRT_HID;
    t2.w = Bz * INV_SQRT_HID;
    tab2[n * HIDc + u] = t2;

    if (u == 0) {
        const float s = C_S * a * INV_SQRT_HID;
        out_scpart[3 * n + 0] = scx * s;
        out_scpart[3 * n + 1] = scy * s;
        out_scpart[3 * n + 2] = scz * s;
    }
}

// ---------------------------------------------------------------------------
// Phase 2 (MFMA, corrected operand layout, NO inline asm):
// wave = 2 nodes (64 edges). D = W^T x X^T with A/B layout
//   lane(col,h): elem e -> k = (e&3) + 8*(e>>2) + 4h  (two half-K blocks)
// C/D: col=lane&31, row=(i&3)+8*(i>>2)+4h  [measured m74/m101].
// Under this layout layer1-out feeds layer2-B with ZERO routing.
// Cross-half routing (B1 only) via __shfl_xor(.,32,64) + selects.
// ---------------------------------------------------------------------------
__global__ __launch_bounds__(256) void se3_phase2(
    const float* __restrict__ coords, const float* __restrict__ t,
    const int* __restrict__ esrc, const float* __restrict__ emask,
    const float* __restrict__ W0, const float* __restrict__ W1,
    const float4* __restrict__ tab2, float* __restrict__ out)
{
    const int lane = threadIdx.x & 63;
    const int col  = lane & 31;
    const int h    = lane >> 5;

    // ---- A1 = W0^T (K=16, zero-padded beyond NB=10) ----
    float a1v[8];
#pragma unroll
    for (int e2 = 0; e2 < 8; ++e2) {
        const int k = (e2 & 3) + 8 * (e2 >> 2) + 4 * h;
        a1v[e2] = (k < NBc) ? W0[k * HIDc + col] : 0.f;
    }
    unsigned a1h_[4], a1l_[4];
#pragma unroll
    for (int j = 0; j < 4; ++j) {
        const float x = a1v[2 * j], y = a1v[2 * j + 1];
        a1h_[j] = pk_hi(x, y);
        a1l_[j] = pk_hi(x - trunc_hi(x), y - trunc_hi(y));
    }
    const bf16x8 A1H = mk_frag(a1h_[0], a1h_[1], a1h_[2], a1h_[3]);
    const bf16x8 A1L = mk_frag(a1l_[0], a1l_[1], a1l_[2], a1l_[3]);

    // ---- A2 = W1^T, K=32 as 2 K-steps of 16 ----
    bf16x8 A2H[2], A2L[2];
#pragma unroll
    for (int ks = 0; ks < 2; ++ks) {
        float w[8];
#pragma unroll
        for (int e2 = 0; e2 < 8; ++e2) {
            const int k = 16 * ks + (e2 & 3) + 8 * (e2 >> 2) + 4 * h;
            w[e2] = W1[k * HIDc + col];
        }
        unsigned rh[4], rl[4];
#pragma unroll
        for (int j = 0; j < 4; ++j) {
            rh[j] = pk_hi(w[2 * j], w[2 * j + 1]);
            rl[j] = pk_hi(w[2 * j] - trunc_hi(w[2 * j]),
                          w[2 * j + 1] - trunc_hi(w[2 * j + 1]));
        }
        A2H[ks] = mk_frag(rh[0], rh[1], rh[2], rh[3]);
        A2L[ks] = mk_frag(rl[0], rl[1], rl[2], rl[3]);
    }

    // ---- per-edge scalar work (lane owns edge g) ----
    const int wid = blockIdx.x * 4 + (threadIdx.x >> 6);
    const int e0  = wid * 64;
    const int g   = e0 + lane;
    const int nA  = e0 >> 5;            // tile0 node; tile1 node = nA+1
    const int myn = g >> 5;
    const int src = esrc[g];
    const float em = emask[g];

    const float dx = coords[3 * myn + 0] - coords[3 * src + 0];
    const float dy = coords[3 * myn + 1] - coords[3 * src + 1];
    const float dz = coords[3 * myn + 2] - coords[3 * src + 2];
    const float r  = sqrtf(dx * dx + dy * dy + dz * dz + 1e-12f);
    const float ir = 1.0f / r;
    const float shx = SQ3 * dx * ir, shy = SQ3 * dy * ir, shz = SQ3 * dz * ir;

    float embv[NBc];
#pragma unroll
    for (int b = 0; b < NBc; ++b) {
        const float d = r * INV_STEP - (float)b;
        embv[b] = __expf(-d * d) * EMB_SCALE;
    }

    // own-edge emb packed: ph[j] = [emb(2j) | emb(2j+1)]
    unsigned ph[5], pl[5];
#pragma unroll
    for (int j = 0; j < 5; ++j) {
        const float a0 = embv[2 * j], b0 = embv[2 * j + 1];
        ph[j] = pk_hi(a0, b0);
        pl[j] = pk_hi(a0 - trunc_hi(a0), b0 - trunc_hi(b0));
    }
    // paired-lane (lane^32) copies
    unsigned oph[5], opl[5];
#pragma unroll
    for (int j = 0; j < 5; ++j) {
        oph[j] = __shfl_xor(ph[j], 32, 64);
        opl[j] = __shfl_xor(pl[j], 32, 64);
    }

    // B1 fragments. Required: B[k][col] = emb_k(tile edge col),
    // k = (e&3)+8*(e>>2)+4h. Tile0 data lives in half0 lanes, tile1 in half1.
    //  tile0: h0 -> k{0..3,8..11}: own ph0,ph1,ph4,0 ; h1 -> k{4..7,12..15}: pair ph2,ph3,0,0
    //  tile1: h0 -> pair ph0,ph1,ph4,0            ; h1 -> own ph2,ph3,0,0
    const bf16x8 B1H0 = mk_frag(h ? oph[2] : ph[0], h ? oph[3] : ph[1], h ? 0u : ph[4], 0u);
    const bf16x8 B1L0 = mk_frag(h ? opl[2] : pl[0], h ? opl[3] : pl[1], h ? 0u : pl[4], 0u);
    const bf16x8 B1H1 = mk_frag(h ? ph[2] : oph[0], h ? ph[3] : oph[1], h ? 0u : oph[4], 0u);
    const bf16x8 B1L1 = mk_frag(h ? pl[2] : opl[0], h ? pl[3] : opl[1], h ? 0u : opl[4], 0u);

    float cxo[2], cyo[2], czo[2];

#pragma unroll
    for (int tI = 0; tI < 2; ++tI) {
        const bf16x8 B1H = tI ? B1H1 : B1H0;
        const bf16x8 B1L = tI ? B1L1 : B1L0;

        f32x16 c;
#pragma unroll
        for (int i = 0; i < 16; ++i) c[i] = 0.f;
        c = mfma32(A1H, B1H, c);
        c = mfma32(A1H, B1L, c);
        c = mfma32(A1L, B1H, c);
        c = mfma32(A1L, B1L, c);

        float h1v[16];
#pragma unroll
        for (int i = 0; i < 16; ++i) h1v[i] = silu_rcp(c[i] * INV_SQRT_NB);

        // layer2 B operand: lane needs h1[16ks + (e&3)+8*(e>>2)+4h] of own col
        // == own h1v[8ks + e]  (zero routing!)
        unsigned PH[8], PL[8];
#pragma unroll
        for (int i = 0; i < 8; ++i) {
            const float a0 = h1v[2 * i], b0 = h1v[2 * i + 1];
            PH[i] = pk_hi(a0, b0);
            PL[i] = pk_hi(a0 - trunc_hi(a0), b0 - trunc_hi(b0));
        }
        const bf16x8 B2H0 = mk_frag(PH[0], PH[1], PH[2], PH[3]);
        const bf16x8 B2L0 = mk_frag(PL[0], PL[1], PL[2], PL[3]);
        const bf16x8 B2H1 = mk_frag(PH[4], PH[5], PH[6], PH[7]);
        const bf16x8 B2L1 = mk_frag(PL[4], PL[5], PL[6], PL[7]);

        f32x16 c2;
#pragma unroll
        for (int i = 0; i < 16; ++i) c2[i] = 0.f;
        c2 = mfma32(A2H[0], B2H0, c2);
        c2 = mfma32(A2H[0], B2L0, c2);
        c2 = mfma32(A2L[0], B2H0, c2);
        c2 = mfma32(A2L[0], B2L0, c2);
        c2 = mfma32(A2H[1], B2H1, c2);
        c2 = mfma32(A2H[1], B2L1, c2);
        c2 = mfma32(A2L[1], B2H1, c2);
        c2 = mfma32(A2L[1], B2L1, c2);

        float h2v[16];
#pragma unroll
        for (int i = 0; i < 16; ++i) h2v[i] = silu_rcp(c2[i] * INV_SQRT_HID);

        // ---- consumption: lanes (col, h0/h1) pair on edge col of node nA+tI
        const int   srcT = __shfl(src, tI * 32 + col, 64);
        const float emT  = __shfl(em,  tI * 32 + col, 64);
        const float sxT  = __shfl(shx, tI * 32 + col, 64);
        const float syT  = __shfl(shy, tI * 32 + col, 64);
        const float szT  = __shfl(shz, tI * 32 + col, 64);

        const float4* __restrict__ tp = tab2 + srcT * HIDc;
        float pp = 0.f, qx = 0.f, qy = 0.f, qz = 0.f;
#pragma unroll
        for (int i = 0; i < 16; ++i) {
            const int u2 = (i & 3) + 8 * (i >> 2) + 4 * h;
            const float4 gq = tp[u2];
            pp = fmaf(h2v[i], gq.x, pp);
            qx = fmaf(h2v[i], gq.y, qx);
            qy = fmaf(h2v[i], gq.z, qy);
            qz = fmaf(h2v[i], gq.w, qz);
        }
        pp += __shfl_xor(pp, 32, 64);
        qx += __shfl_xor(qx, 32, 64);
        qy += __shfl_xor(qy, 32, 64);
        qz += __shfl_xor(qz, 32, 64);

        float cx = emT * fmaf(pp, sxT, qx);
        float cy = emT * fmaf(pp, syT, qy);
        float cz = emT * fmaf(pp, szT, qz);
#pragma unroll
        for (int m = 16; m >= 1; m >>= 1) {
            cx += __shfl_xor(cx, m, 64);
            cy += __shfl_xor(cy, m, 64);
            cz += __shfl_xor(cz, m, 64);
        }
        cxo[tI] = cx; cyo[tI] = cy; czo[tI] = cz;
    }

    if (lane < 2) {
        const int n = nA + lane;
        const float a = t[n >> 8];
        const float s = C_X * a * INV_SQRT_2HID * INV_SQRT_K;
        const float vx = lane ? cxo[1] : cxo[0];
        const float vy = lane ? cyo[1] : cyo[0];
        const float vz = lane ? czo[1] : czo[0];
        out[3 * n + 0] += vx * s;
        out[3 * n + 1] += vy * s;
        out[3 * n + 2] += vz * s;
    }
}

extern "C" void kernel_launch(void* const* d_in, const int* in_sizes, int n_in,
                              void* d_out, int out_size, void* d_ws, size_t ws_size,
                              hipStream_t stream) {
    const float* coords = (const float*)d_in[0];
    const float* t      = (const float*)d_in[1];
    const int*   batch  = (const int*)d_in[2];
    const int*   esrc   = (const int*)d_in[3];
    const float* emask  = (const float*)d_in[5];
    const float* sc1_w  = (const float*)d_in[6];
    const float* lin1_w = (const float*)d_in[7];
    const float* fc1_w0 = (const float*)d_in[8];
    const float* fc1_w1 = (const float*)d_in[9];
    const float* fc1_w2 = (const float*)d_in[10];
    const float* c1l2s  = (const float*)d_in[11];
    const float* c1l2v  = (const float*)d_in[12];
    const float* sc2_w  = (const float*)d_in[13];
    const float* lin1s  = (const float*)d_in[14];
    const float* lin1v  = (const float*)d_in[15];
    const float* fc2_w0 = (const float*)d_in[16];
    const float* fc2_w1 = (const float*)d_in[17];
    const float* fc2_w2 = (const float*)d_in[18];
    const float* c2a    = (const float*)d_in[19];
    const float* c2b    = (const float*)d_in[20];

    float*  out  = (float*)d_out;
    float4* tab2 = (float4*)d_ws;          // N*HID float4 = 8 MB (proven footprint)

    const int nEdges = 16384 * Kc;         // 524288
    dim3 block(256);
    dim3 grid(nEdges / 256);               // 2048 blocks

    se3_phase1<<<grid, block, 0, stream>>>(coords, t, batch, esrc, emask,
        sc1_w, lin1_w, fc1_w0, fc1_w1, fc1_w2, c1l2s, c1l2v, sc2_w,
        lin1s, lin1v, c2a, c2b, fc2_w2, tab2, out);

    se3_phase2<<<grid, block, 0, stream>>>(coords, t, esrc, emask,
        fc2_w0, fc2_w1, tab2, out);
}

// Round 6
// 151.668 us; speedup vs baseline: 1.3692x; 1.0716x over previous
//
#include <hip/hip_runtime.h>

namespace {
constexpr int Kc = 32, HIDc = 32, NBc = 10;
constexpr float C_S = 0.3826834323650898f;   // sin(pi/8)
constexpr float C_X = 0.9238795325112867f;   // cos(pi/8)
constexpr float SQ3 = 1.7320508075688772f;
constexpr float INV_SQRT_K   = 0.17677669529663687f;  // 1/sqrt(32)
constexpr float INV_SQRT_HID = 0.17677669529663687f;  // 1/sqrt(32)
constexpr float INV_SQRT_NB  = 0.31622776601683794f;  // 1/sqrt(10)
constexpr float INV_SQRT_2HID = 0.125f;               // 1/sqrt(64)
constexpr float INV_STEP  = 1.8f;                     // 1/(5/9)
constexpr float EMB_SCALE = 0.8928571428571429f;      // 1/1.12

typedef __attribute__((ext_vector_type(8)))  short bf16x8;
typedef __attribute__((ext_vector_type(16))) float f32x16;
typedef __attribute__((ext_vector_type(4)))  int   i32x4;

__device__ __forceinline__ float silu_div(float x) {
    return x / (1.0f + __expf(-x));
}
__device__ __forceinline__ float silu_rcp(float x) {
    return x * __builtin_amdgcn_rcpf(1.0f + __expf(-x));
}

// pack two f32 into one VGPR as 2 bf16 (truncation): low16=bf16(a), high16=bf16(b)
__device__ __forceinline__ unsigned pk_hi(float a, float b) {
    unsigned ua = __builtin_bit_cast(unsigned, a);
    unsigned ub = __builtin_bit_cast(unsigned, b);
    return (ua >> 16) | (ub & 0xFFFF0000u);
}
__device__ __forceinline__ float trunc_hi(float a) {
    return __builtin_bit_cast(float, __builtin_bit_cast(unsigned, a) & 0xFFFF0000u);
}
__device__ __forceinline__ bf16x8 mk_frag(unsigned r0, unsigned r1, unsigned r2, unsigned r3) {
    i32x4 t; t[0] = (int)r0; t[1] = (int)r1; t[2] = (int)r2; t[3] = (int)r3;
    return __builtin_bit_cast(bf16x8, t);
}
__device__ __forceinline__ f32x16 mfma32(bf16x8 a, bf16x8 b, f32x16 c) {
    return __builtin_amdgcn_mfma_f32_32x32x16_bf16(a, b, c, 0, 0, 0);
}
} // namespace

// ---------------------------------------------------------------------------
// Phase 1 (MFMA edge-MLP, verified layout from R5 phase2):
// wave = 2 nodes (64 edges). Radial MLP #1 via MFMA; final 32->2 layer as
// per-lane 16-elem partial dots + pair-sum. Then the R2-proven butterfly
// segment sums + node phase + tab2 epilogue (byte-identical).
// A/B k-layout: lane(col,h), elem e -> k = (e&3)+8*(e>>2)+4h.
// C/D: col=lane&31, row=(i&3)+8*(i>>2)+4h.
// ---------------------------------------------------------------------------
__global__ __launch_bounds__(256) void se3_phase1(
    const float* __restrict__ coords, const float* __restrict__ t,
    const int* __restrict__ batch, const int* __restrict__ esrc,
    const float* __restrict__ emask,
    const float* __restrict__ sc1_w, const float* __restrict__ lin1_w,
    const float* __restrict__ W0, const float* __restrict__ W1,
    const float* __restrict__ W2,
    const float* __restrict__ l2s, const float* __restrict__ l2v,
    const float* __restrict__ sc2_w, const float* __restrict__ lin1s,
    const float* __restrict__ lin1v,
    const float* __restrict__ c2a, const float* __restrict__ c2b,
    const float* __restrict__ W2f2,
    float4* __restrict__ tab2, float* __restrict__ out_scpart)
{
    const int lane = threadIdx.x & 63;
    const int col  = lane & 31;
    const int h    = lane >> 5;

    // ---- A1 = W0^T (K=16, zero-padded beyond NB=10) ----
    float a1v[8];
#pragma unroll
    for (int e2 = 0; e2 < 8; ++e2) {
        const int k = (e2 & 3) + 8 * (e2 >> 2) + 4 * h;
        a1v[e2] = (k < NBc) ? W0[k * HIDc + col] : 0.f;
    }
    unsigned a1h_[4], a1l_[4];
#pragma unroll
    for (int j = 0; j < 4; ++j) {
        const float x = a1v[2 * j], y = a1v[2 * j + 1];
        a1h_[j] = pk_hi(x, y);
        a1l_[j] = pk_hi(x - trunc_hi(x), y - trunc_hi(y));
    }
    const bf16x8 A1H = mk_frag(a1h_[0], a1h_[1], a1h_[2], a1h_[3]);
    const bf16x8 A1L = mk_frag(a1l_[0], a1l_[1], a1l_[2], a1l_[3]);

    // ---- A2 = W1^T, K=32 as 2 K-steps of 16 ----
    bf16x8 A2H[2], A2L[2];
#pragma unroll
    for (int ks = 0; ks < 2; ++ks) {
        float w[8];
#pragma unroll
        for (int e2 = 0; e2 < 8; ++e2) {
            const int k = 16 * ks + (e2 & 3) + 8 * (e2 >> 2) + 4 * h;
            w[e2] = W1[k * HIDc + col];
        }
        unsigned rh[4], rl[4];
#pragma unroll
        for (int j = 0; j < 4; ++j) {
            rh[j] = pk_hi(w[2 * j], w[2 * j + 1]);
            rl[j] = pk_hi(w[2 * j] - trunc_hi(w[2 * j]),
                          w[2 * j + 1] - trunc_hi(w[2 * j + 1]));
        }
        A2H[ks] = mk_frag(rh[0], rh[1], rh[2], rh[3]);
        A2L[ks] = mk_frag(rl[0], rl[1], rl[2], rl[3]);
    }

    // ---- final-layer weights for this lane's 16 rows (tI-invariant) ----
    float w2a[16], w2b[16];
#pragma unroll
    for (int i = 0; i < 16; ++i) {
        const int u2 = (i & 3) + 8 * (i >> 2) + 4 * h;
        w2a[i] = W2[2 * u2 + 0];
        w2b[i] = W2[2 * u2 + 1];
    }

    // ---- per-edge scalar work (lane owns edge g) ----
    const int wid = blockIdx.x * 4 + (threadIdx.x >> 6);
    const int e0  = wid * 64;
    const int g   = e0 + lane;
    const int n   = g >> 5;             // own node (half0 -> nA, half1 -> nA+1)
    const int u   = col;
    const int src = esrc[g];
    const float em = emask[g];

    const float dx = coords[3 * n + 0] - coords[3 * src + 0];
    const float dy = coords[3 * n + 1] - coords[3 * src + 1];
    const float dz = coords[3 * n + 2] - coords[3 * src + 2];
    const float r  = sqrtf(dx * dx + dy * dy + dz * dz + 1e-12f);
    const float ir = 1.0f / r;
    const float shx = SQ3 * dx * ir, shy = SQ3 * dy * ir, shz = SQ3 * dz * ir;

    float embv[NBc];
#pragma unroll
    for (int b = 0; b < NBc; ++b) {
        const float d = r * INV_STEP - (float)b;
        embv[b] = __expf(-d * d) * EMB_SCALE;
    }

    unsigned ph[5], pl[5];
#pragma unroll
    for (int j = 0; j < 5; ++j) {
        const float a0 = embv[2 * j], b0 = embv[2 * j + 1];
        ph[j] = pk_hi(a0, b0);
        pl[j] = pk_hi(a0 - trunc_hi(a0), b0 - trunc_hi(b0));
    }
    unsigned oph[5], opl[5];
#pragma unroll
    for (int j = 0; j < 5; ++j) {
        oph[j] = __shfl_xor(ph[j], 32, 64);
        opl[j] = __shfl_xor(pl[j], 32, 64);
    }

    const bf16x8 B1H0 = mk_frag(h ? oph[2] : ph[0], h ? oph[3] : ph[1], h ? 0u : ph[4], 0u);
    const bf16x8 B1L0 = mk_frag(h ? opl[2] : pl[0], h ? opl[3] : pl[1], h ? 0u : pl[4], 0u);
    const bf16x8 B1H1 = mk_frag(h ? ph[2] : oph[0], h ? ph[3] : oph[1], h ? 0u : oph[4], 0u);
    const bf16x8 B1L1 = mk_frag(h ? pl[2] : opl[0], h ? pl[3] : opl[1], h ? 0u : opl[4], 0u);

    float w10t[2], w11t[2];

#pragma unroll
    for (int tI = 0; tI < 2; ++tI) {
        const bf16x8 B1H = tI ? B1H1 : B1H0;
        const bf16x8 B1L = tI ? B1L1 : B1L0;

        f32x16 c;
#pragma unroll
        for (int i = 0; i < 16; ++i) c[i] = 0.f;
        c = mfma32(A1H, B1H, c);
        c = mfma32(A1H, B1L, c);
        c = mfma32(A1L, B1H, c);
        c = mfma32(A1L, B1L, c);

        float h1v[16];
#pragma unroll
        for (int i = 0; i < 16; ++i) h1v[i] = silu_rcp(c[i] * INV_SQRT_NB);

        unsigned PH[8], PL[8];
#pragma unroll
        for (int i = 0; i < 8; ++i) {
            const float a0 = h1v[2 * i], b0 = h1v[2 * i + 1];
            PH[i] = pk_hi(a0, b0);
            PL[i] = pk_hi(a0 - trunc_hi(a0), b0 - trunc_hi(b0));
        }
        const bf16x8 B2H0 = mk_frag(PH[0], PH[1], PH[2], PH[3]);
        const bf16x8 B2L0 = mk_frag(PL[0], PL[1], PL[2], PL[3]);
        const bf16x8 B2H1 = mk_frag(PH[4], PH[5], PH[6], PH[7]);
        const bf16x8 B2L1 = mk_frag(PL[4], PL[5], PL[6], PL[7]);

        f32x16 c2;
#pragma unroll
        for (int i = 0; i < 16; ++i) c2[i] = 0.f;
        c2 = mfma32(A2H[0], B2H0, c2);
        c2 = mfma32(A2H[0], B2L0, c2);
        c2 = mfma32(A2L[0], B2H0, c2);
        c2 = mfma32(A2L[0], B2L0, c2);
        c2 = mfma32(A2H[1], B2H1, c2);
        c2 = mfma32(A2H[1], B2L1, c2);
        c2 = mfma32(A2L[1], B2H1, c2);
        c2 = mfma32(A2L[1], B2L1, c2);

        // final 32->2 layer: partial dot over this lane's 16 rows
        float pw0 = 0.f, pw1 = 0.f;
#pragma unroll
        for (int i = 0; i < 16; ++i) {
            const float h2i = silu_rcp(c2[i] * INV_SQRT_HID);
            pw0 = fmaf(h2i, w2a[i], pw0);
            pw1 = fmaf(h2i, w2b[i], pw1);
        }
        pw0 += __shfl_xor(pw0, 32, 64);
        pw1 += __shfl_xor(pw1, 32, 64);
        w10t[tI] = pw0;
        w11t[tI] = pw1;
    }

    // owner-select: lane's own edge belongs to tile h
    const float w10 = (h ? w10t[1] : w10t[0]) * INV_SQRT_HID;
    const float w11 = (h ? w11t[1] : w11t[0]) * INV_SQRT_HID;

    const float xs = t[batch[src]] * lin1_w[0];
    float ms = w10 * xs * em;
    const float fv = w11 * xs * em;
    float mvx = fv * shx, mvy = fv * shy, mvz = fv * shz;

#pragma unroll
    for (int m = 16; m >= 1; m >>= 1) {
        ms  += __shfl_xor(ms,  m, 32);
        mvx += __shfl_xor(mvx, m, 32);
        mvy += __shfl_xor(mvy, m, 32);
        mvz += __shfl_xor(mvz, m, 32);
    }
    const float nms = ms  * INV_SQRT_K;
    const float nvx = mvx * INV_SQRT_K;
    const float nvy = mvy * INV_SQRT_K;
    const float nvz = mvz * INV_SQRT_K;

    // ---- node phase (R2-proven): lane owns hidden unit u of node n ----
    const float a  = t[batch[n]];
    const float hs = silu_div(C_S * a * sc1_w[u] + C_X * nms * a * l2s[u]);
    const float lv = l2v[u];
    const float hvx = silu_div(C_X * nvx * a * lv);
    const float hvy = silu_div(C_X * nvy * a * lv);
    const float hvz = silu_div(C_X * nvz * a * lv);

    const float s2 = sc2_w[u];
    float scx = hvx * s2, scy = hvy * s2, scz = hvz * s2;
#pragma unroll
    for (int m = 16; m >= 1; m >>= 1) {
        scx += __shfl_xor(scx, m, 32);
        scy += __shfl_xor(scy, m, 32);
        scz += __shfl_xor(scz, m, 32);
    }

    float s1 = 0.f, v1x = 0.f, v1y = 0.f, v1z = 0.f;
    for (int v = 0; v < HIDc; ++v) {
        const float hsv = __shfl(hs,  v, 32);
        const float hx  = __shfl(hvx, v, 32);
        const float hy  = __shfl(hvy, v, 32);
        const float hz  = __shfl(hvz, v, 32);
        const float wsv = lin1s[v * HIDc + u];
        const float wvv = lin1v[v * HIDc + u];
        s1  = fmaf(hsv, wsv, s1);
        v1x = fmaf(hx, wvv, v1x);
        v1y = fmaf(hy, wvv, v1y);
        v1z = fmaf(hz, wvv, v1z);
    }
    const float sa = INV_SQRT_HID * a;
    const float ox_ = s1  * sa * c2a[u];
    const float oy_ = v1x * sa * c2b[u];
    const float oz_ = v1y * sa * c2b[u];
    const float ow_ = v1z * sa * c2b[u];

    float A = 0.f, Bx = 0.f, By = 0.f, Bz = 0.f;
#pragma unroll
    for (int j = 0; j < HIDc; ++j) {
        const float ojx = __shfl(ox_, j, 32);
        const float ojy = __shfl(oy_, j, 32);
        const float ojz = __shfl(oz_, j, 32);
        const float ojw = __shfl(ow_, j, 32);
        const float wa  = W2f2[u * 64 + j];
        const float wb  = W2f2[u * 64 + 32 + j];
        A  = fmaf(wa, ojx, A);
        Bx = fmaf(wb, ojy, Bx);
        By = fmaf(wb, ojz, By);
        Bz = fmaf(wb, ojw, Bz);
    }
    float4 t2;
    t2.x = A  * INV_SQRT_HID;
    t2.y = Bx * INV_SQRT_HID;
    t2.z = By * INV_SQRT_HID;
    t2.w = Bz * INV_SQRT_HID;
    tab2[n * HIDc + u] = t2;

    if (u == 0) {
        const float s = C_S * a * INV_SQRT_HID;
        out_scpart[3 * n + 0] = scx * s;
        out_scpart[3 * n + 1] = scy * s;
        out_scpart[3 * n + 2] = scz * s;
    }
}

// ---------------------------------------------------------------------------
// Phase 2 — byte-identical to the R5 version that passed.
// ---------------------------------------------------------------------------
__global__ __launch_bounds__(256) void se3_phase2(
    const float* __restrict__ coords, const float* __restrict__ t,
    const int* __restrict__ esrc, const float* __restrict__ emask,
    const float* __restrict__ W0, const float* __restrict__ W1,
    const float4* __restrict__ tab2, float* __restrict__ out)
{
    const int lane = threadIdx.x & 63;
    const int col  = lane & 31;
    const int h    = lane >> 5;

    float a1v[8];
#pragma unroll
    for (int e2 = 0; e2 < 8; ++e2) {
        const int k = (e2 & 3) + 8 * (e2 >> 2) + 4 * h;
        a1v[e2] = (k < NBc) ? W0[k * HIDc + col] : 0.f;
    }
    unsigned a1h_[4], a1l_[4];
#pragma unroll
    for (int j = 0; j < 4; ++j) {
        const float x = a1v[2 * j], y = a1v[2 * j + 1];
        a1h_[j] = pk_hi(x, y);
        a1l_[j] = pk_hi(x - trunc_hi(x), y - trunc_hi(y));
    }
    const bf16x8 A1H = mk_frag(a1h_[0], a1h_[1], a1h_[2], a1h_[3]);
    const bf16x8 A1L = mk_frag(a1l_[0], a1l_[1], a1l_[2], a1l_[3]);

    bf16x8 A2H[2], A2L[2];
#pragma unroll
    for (int ks = 0; ks < 2; ++ks) {
        float w[8];
#pragma unroll
        for (int e2 = 0; e2 < 8; ++e2) {
            const int k = 16 * ks + (e2 & 3) + 8 * (e2 >> 2) + 4 * h;
            w[e2] = W1[k * HIDc + col];
        }
        unsigned rh[4], rl[4];
#pragma unroll
        for (int j = 0; j < 4; ++j) {
            rh[j] = pk_hi(w[2 * j], w[2 * j + 1]);
            rl[j] = pk_hi(w[2 * j] - trunc_hi(w[2 * j]),
                          w[2 * j + 1] - trunc_hi(w[2 * j + 1]));
        }
        A2H[ks] = mk_frag(rh[0], rh[1], rh[2], rh[3]);
        A2L[ks] = mk_frag(rl[0], rl[1], rl[2], rl[3]);
    }

    const int wid = blockIdx.x * 4 + (threadIdx.x >> 6);
    const int e0  = wid * 64;
    const int g   = e0 + lane;
    const int nA  = e0 >> 5;
    const int myn = g >> 5;
    const int src = esrc[g];
    const float em = emask[g];

    const float dx = coords[3 * myn + 0] - coords[3 * src + 0];
    const float dy = coords[3 * myn + 1] - coords[3 * src + 1];
    const float dz = coords[3 * myn + 2] - coords[3 * src + 2];
    const float r  = sqrtf(dx * dx + dy * dy + dz * dz + 1e-12f);
    const float ir = 1.0f / r;
    const float shx = SQ3 * dx * ir, shy = SQ3 * dy * ir, shz = SQ3 * dz * ir;

    float embv[NBc];
#pragma unroll
    for (int b = 0; b < NBc; ++b) {
        const float d = r * INV_STEP - (float)b;
        embv[b] = __expf(-d * d) * EMB_SCALE;
    }

    unsigned ph[5], pl[5];
#pragma unroll
    for (int j = 0; j < 5; ++j) {
        const float a0 = embv[2 * j], b0 = embv[2 * j + 1];
        ph[j] = pk_hi(a0, b0);
        pl[j] = pk_hi(a0 - trunc_hi(a0), b0 - trunc_hi(b0));
    }
    unsigned oph[5], opl[5];
#pragma unroll
    for (int j = 0; j < 5; ++j) {
        oph[j] = __shfl_xor(ph[j], 32, 64);
        opl[j] = __shfl_xor(pl[j], 32, 64);
    }

    const bf16x8 B1H0 = mk_frag(h ? oph[2] : ph[0], h ? oph[3] : ph[1], h ? 0u : ph[4], 0u);
    const bf16x8 B1L0 = mk_frag(h ? opl[2] : pl[0], h ? opl[3] : pl[1], h ? 0u : pl[4], 0u);
    const bf16x8 B1H1 = mk_frag(h ? ph[2] : oph[0], h ? ph[3] : oph[1], h ? 0u : oph[4], 0u);
    const bf16x8 B1L1 = mk_frag(h ? pl[2] : opl[0], h ? pl[3] : opl[1], h ? 0u : opl[4], 0u);

    float cxo[2], cyo[2], czo[2];

#pragma unroll
    for (int tI = 0; tI < 2; ++tI) {
        const bf16x8 B1H = tI ? B1H1 : B1H0;
        const bf16x8 B1L = tI ? B1L1 : B1L0;

        f32x16 c;
#pragma unroll
        for (int i = 0; i < 16; ++i) c[i] = 0.f;
        c = mfma32(A1H, B1H, c);
        c = mfma32(A1H, B1L, c);
        c = mfma32(A1L, B1H, c);
        c = mfma32(A1L, B1L, c);

        float h1v[16];
#pragma unroll
        for (int i = 0; i < 16; ++i) h1v[i] = silu_rcp(c[i] * INV_SQRT_NB);

        unsigned PH[8], PL[8];
#pragma unroll
        for (int i = 0; i < 8; ++i) {
            const float a0 = h1v[2 * i], b0 = h1v[2 * i + 1];
            PH[i] = pk_hi(a0, b0);
            PL[i] = pk_hi(a0 - trunc_hi(a0), b0 - trunc_hi(b0));
        }
        const bf16x8 B2H0 = mk_frag(PH[0], PH[1], PH[2], PH[3]);
        const bf16x8 B2L0 = mk_frag(PL[0], PL[1], PL[2], PL[3]);
        const bf16x8 B2H1 = mk_frag(PH[4], PH[5], PH[6], PH[7]);
        const bf16x8 B2L1 = mk_frag(PL[4], PL[5], PL[6], PL[7]);

        f32x16 c2;
#pragma unroll
        for (int i = 0; i < 16; ++i) c2[i] = 0.f;
        c2 = mfma32(A2H[0], B2H0, c2);
        c2 = mfma32(A2H[0], B2L0, c2);
        c2 = mfma32(A2L[0], B2H0, c2);
        c2 = mfma32(A2L[0], B2L0, c2);
        c2 = mfma32(A2H[1], B2H1, c2);
        c2 = mfma32(A2H[1], B2L1, c2);
        c2 = mfma32(A2L[1], B2H1, c2);
        c2 = mfma32(A2L[1], B2L1, c2);

        float h2v[16];
#pragma unroll
        for (int i = 0; i < 16; ++i) h2v[i] = silu_rcp(c2[i] * INV_SQRT_HID);

        const int   srcT = __shfl(src, tI * 32 + col, 64);
        const float emT  = __shfl(em,  tI * 32 + col, 64);
        const float sxT  = __shfl(shx, tI * 32 + col, 64);
        const float syT  = __shfl(shy, tI * 32 + col, 64);
        const float szT  = __shfl(shz, tI * 32 + col, 64);

        const float4* __restrict__ tp = tab2 + srcT * HIDc;
        float pp = 0.f, qx = 0.f, qy = 0.f, qz = 0.f;
#pragma unroll
        for (int i = 0; i < 16; ++i) {
            const int u2 = (i & 3) + 8 * (i >> 2) + 4 * h;
            const float4 gq = tp[u2];
            pp = fmaf(h2v[i], gq.x, pp);
            qx = fmaf(h2v[i], gq.y, qx);
            qy = fmaf(h2v[i], gq.z, qy);
            qz = fmaf(h2v[i], gq.w, qz);
        }
        pp += __shfl_xor(pp, 32, 64);
        qx += __shfl_xor(qx, 32, 64);
        qy += __shfl_xor(qy, 32, 64);
        qz += __shfl_xor(qz, 32, 64);

        float cx = emT * fmaf(pp, sxT, qx);
        float cy = emT * fmaf(pp, syT, qy);
        float cz = emT * fmaf(pp, szT, qz);
#pragma unroll
        for (int m = 16; m >= 1; m >>= 1) {
            cx += __shfl_xor(cx, m, 64);
            cy += __shfl_xor(cy, m, 64);
            cz += __shfl_xor(cz, m, 64);
        }
        cxo[tI] = cx; cyo[tI] = cy; czo[tI] = cz;
    }

    if (lane < 2) {
        const int n = nA + lane;
        const float a = t[n >> 8];
        const float s = C_X * a * INV_SQRT_2HID * INV_SQRT_K;
        const float vx = lane ? cxo[1] : cxo[0];
        const float vy = lane ? cyo[1] : cyo[0];
        const float vz = lane ? czo[1] : czo[0];
        out[3 * n + 0] += vx * s;
        out[3 * n + 1] += vy * s;
        out[3 * n + 2] += vz * s;
    }
}

extern "C" void kernel_launch(void* const* d_in, const int* in_sizes, int n_in,
                              void* d_out, int out_size, void* d_ws, size_t ws_size,
                              hipStream_t stream) {
    const float* coords = (const float*)d_in[0];
    const float* t      = (const float*)d_in[1];
    const int*   batch  = (const int*)d_in[2];
    const int*   esrc   = (const int*)d_in[3];
    const float* emask  = (const float*)d_in[5];
    const float* sc1_w  = (const float*)d_in[6];
    const float* lin1_w = (const float*)d_in[7];
    const float* fc1_w0 = (const float*)d_in[8];
    const float* fc1_w1 = (const float*)d_in[9];
    const float* fc1_w2 = (const float*)d_in[10];
    const float* c1l2s  = (const float*)d_in[11];
    const float* c1l2v  = (const float*)d_in[12];
    const float* sc2_w  = (const float*)d_in[13];
    const float* lin1s  = (const float*)d_in[14];
    const float* lin1v  = (const float*)d_in[15];
    const float* fc2_w0 = (const float*)d_in[16];
    const float* fc2_w1 = (const float*)d_in[17];
    const float* fc2_w2 = (const float*)d_in[18];
    const float* c2a    = (const float*)d_in[19];
    const float* c2b    = (const float*)d_in[20];

    float*  out  = (float*)d_out;
    float4* tab2 = (float4*)d_ws;          // N*HID float4 = 8 MB (proven footprint)

    const int nEdges = 16384 * Kc;         // 524288
    dim3 block(256);
    dim3 grid(nEdges / 256);               // 2048 blocks

    se3_phase1<<<grid, block, 0, stream>>>(coords, t, batch, esrc, emask,
        sc1_w, lin1_w, fc1_w0, fc1_w1, fc1_w2, c1l2s, c1l2v, sc2_w,
        lin1s, lin1v, c2a, c2b, fc2_w2, tab2, out);

    se3_phase2<<<grid, block, 0, stream>>>(coords, t, esrc, emask,
        fc2_w0, fc2_w1, tab2, out);
}

// Round 7
// 149.311 us; speedup vs baseline: 1.3909x; 1.0158x over previous
//
#include <hip/hip_runtime.h>

namespace {
constexpr int Kc = 32, HIDc = 32, NBc = 10;
constexpr float C_S = 0.3826834323650898f;   // sin(pi/8)
constexpr float C_X = 0.9238795325112867f;   // cos(pi/8)
constexpr float SQ3 = 1.7320508075688772f;
constexpr float INV_SQRT_K   = 0.17677669529663687f;  // 1/sqrt(32)
constexpr float INV_SQRT_HID = 0.17677669529663687f;  // 1/sqrt(32)
constexpr float INV_SQRT_NB  = 0.31622776601683794f;  // 1/sqrt(10)
constexpr float INV_SQRT_2HID = 0.125f;               // 1/sqrt(64)
constexpr float INV_STEP  = 1.8f;                     // 1/(5/9)
constexpr float EMB_SCALE = 0.8928571428571429f;      // 1/1.12

typedef __attribute__((ext_vector_type(8)))  short bf16x8;
typedef __attribute__((ext_vector_type(16))) float f32x16;
typedef __attribute__((ext_vector_type(4)))  int   i32x4;

__device__ __forceinline__ float silu_div(float x) {
    return x / (1.0f + __expf(-x));
}
__device__ __forceinline__ float silu_rcp(float x) {
    return x * __builtin_amdgcn_rcpf(1.0f + __expf(-x));
}

// pack two f32 into one VGPR as 2 bf16 (truncation): low16=bf16(a), high16=bf16(b)
__device__ __forceinline__ unsigned pk_hi(float a, float b) {
    unsigned ua = __builtin_bit_cast(unsigned, a);
    unsigned ub = __builtin_bit_cast(unsigned, b);
    return (ua >> 16) | (ub & 0xFFFF0000u);
}
__device__ __forceinline__ float trunc_hi(float a) {
    return __builtin_bit_cast(float, __builtin_bit_cast(unsigned, a) & 0xFFFF0000u);
}
__device__ __forceinline__ bf16x8 mk_frag(unsigned r0, unsigned r1, unsigned r2, unsigned r3) {
    i32x4 t; t[0] = (int)r0; t[1] = (int)r1; t[2] = (int)r2; t[3] = (int)r3;
    return __builtin_bit_cast(bf16x8, t);
}
__device__ __forceinline__ f32x16 mfma32(bf16x8 a, bf16x8 b, f32x16 c) {
    return __builtin_amdgcn_mfma_f32_32x32x16_bf16(a, b, c, 0, 0, 0);
}
} // namespace

// ---------------------------------------------------------------------------
// Precompute (once per launch, 2048 threads):
//   MsT[v*32+u] = Sum_j W2f2[u*64+j]    * c2a[j] * lin1s[v*32+j]
//   MvT[v*32+u] = Sum_j W2f2[u*64+32+j] * c2b[j] * lin1v[v*32+j]
// Folds {lin1s/lin1v matvec} o {diag(c2a/c2b)} o {fc2_w2 contraction} so the
// phase1 node phase needs ONE 32-iter loop instead of two.
// ---------------------------------------------------------------------------
__global__ __launch_bounds__(256) void se3_pre(
    const float* __restrict__ lin1s, const float* __restrict__ lin1v,
    const float* __restrict__ W2f2,
    const float* __restrict__ c2a, const float* __restrict__ c2b,
    float* __restrict__ MsT, float* __restrict__ MvT)
{
    const int id = blockIdx.x * 256 + threadIdx.x;   // 0..2047
    const int v = (id & 1023) >> 5;
    const int u = id & 31;
    float acc = 0.f;
    if (id < 1024) {
#pragma unroll
        for (int j = 0; j < 32; ++j)
            acc = fmaf(W2f2[u * 64 + j] * c2a[j], lin1s[v * 32 + j], acc);
        MsT[v * 32 + u] = acc;
    } else {
#pragma unroll
        for (int j = 0; j < 32; ++j)
            acc = fmaf(W2f2[u * 64 + 32 + j] * c2b[j], lin1v[v * 32 + j], acc);
        MvT[v * 32 + u] = acc;
    }
}

// ---------------------------------------------------------------------------
// Phase 1 (MFMA edge-MLP, R6-verified): wave = 2 nodes (64 edges).
// Node phase now uses the folded MsT/MvT single loop.
// ---------------------------------------------------------------------------
__global__ __launch_bounds__(256) void se3_phase1(
    const float* __restrict__ coords, const float* __restrict__ t,
    const int* __restrict__ batch, const int* __restrict__ esrc,
    const float* __restrict__ emask,
    const float* __restrict__ sc1_w, const float* __restrict__ lin1_w,
    const float* __restrict__ W0, const float* __restrict__ W1,
    const float* __restrict__ W2,
    const float* __restrict__ l2s, const float* __restrict__ l2v,
    const float* __restrict__ sc2_w,
    const float* __restrict__ MsT, const float* __restrict__ MvT,
    float4* __restrict__ tab2, float* __restrict__ out_scpart)
{
    const int lane = threadIdx.x & 63;
    const int col  = lane & 31;
    const int h    = lane >> 5;

    // ---- A1 = W0^T (K=16, zero-padded beyond NB=10) ----
    float a1v[8];
#pragma unroll
    for (int e2 = 0; e2 < 8; ++e2) {
        const int k = (e2 & 3) + 8 * (e2 >> 2) + 4 * h;
        a1v[e2] = (k < NBc) ? W0[k * HIDc + col] : 0.f;
    }
    unsigned a1h_[4], a1l_[4];
#pragma unroll
    for (int j = 0; j < 4; ++j) {
        const float x = a1v[2 * j], y = a1v[2 * j + 1];
        a1h_[j] = pk_hi(x, y);
        a1l_[j] = pk_hi(x - trunc_hi(x), y - trunc_hi(y));
    }
    const bf16x8 A1H = mk_frag(a1h_[0], a1h_[1], a1h_[2], a1h_[3]);
    const bf16x8 A1L = mk_frag(a1l_[0], a1l_[1], a1l_[2], a1l_[3]);

    // ---- A2 = W1^T, K=32 as 2 K-steps of 16 ----
    bf16x8 A2H[2], A2L[2];
#pragma unroll
    for (int ks = 0; ks < 2; ++ks) {
        float w[8];
#pragma unroll
        for (int e2 = 0; e2 < 8; ++e2) {
            const int k = 16 * ks + (e2 & 3) + 8 * (e2 >> 2) + 4 * h;
            w[e2] = W1[k * HIDc + col];
        }
        unsigned rh[4], rl[4];
#pragma unroll
        for (int j = 0; j < 4; ++j) {
            rh[j] = pk_hi(w[2 * j], w[2 * j + 1]);
            rl[j] = pk_hi(w[2 * j] - trunc_hi(w[2 * j]),
                          w[2 * j + 1] - trunc_hi(w[2 * j + 1]));
        }
        A2H[ks] = mk_frag(rh[0], rh[1], rh[2], rh[3]);
        A2L[ks] = mk_frag(rl[0], rl[1], rl[2], rl[3]);
    }

    // ---- final-layer weights for this lane's 16 rows (tI-invariant) ----
    float w2a[16], w2b[16];
#pragma unroll
    for (int i = 0; i < 16; ++i) {
        const int u2 = (i & 3) + 8 * (i >> 2) + 4 * h;
        w2a[i] = W2[2 * u2 + 0];
        w2b[i] = W2[2 * u2 + 1];
    }

    // ---- per-edge scalar work (lane owns edge g) ----
    const int wid = blockIdx.x * 4 + (threadIdx.x >> 6);
    const int e0  = wid * 64;
    const int g   = e0 + lane;
    const int n   = g >> 5;             // own node (half0 -> nA, half1 -> nA+1)
    const int u   = col;
    const int src = esrc[g];
    const float em = emask[g];

    const float dx = coords[3 * n + 0] - coords[3 * src + 0];
    const float dy = coords[3 * n + 1] - coords[3 * src + 1];
    const float dz = coords[3 * n + 2] - coords[3 * src + 2];
    const float r  = sqrtf(dx * dx + dy * dy + dz * dz + 1e-12f);
    const float ir = 1.0f / r;
    const float shx = SQ3 * dx * ir, shy = SQ3 * dy * ir, shz = SQ3 * dz * ir;

    float embv[NBc];
#pragma unroll
    for (int b = 0; b < NBc; ++b) {
        const float d = r * INV_STEP - (float)b;
        embv[b] = __expf(-d * d) * EMB_SCALE;
    }

    unsigned ph[5], pl[5];
#pragma unroll
    for (int j = 0; j < 5; ++j) {
        const float a0 = embv[2 * j], b0 = embv[2 * j + 1];
        ph[j] = pk_hi(a0, b0);
        pl[j] = pk_hi(a0 - trunc_hi(a0), b0 - trunc_hi(b0));
    }
    unsigned oph[5], opl[5];
#pragma unroll
    for (int j = 0; j < 5; ++j) {
        oph[j] = __shfl_xor(ph[j], 32, 64);
        opl[j] = __shfl_xor(pl[j], 32, 64);
    }

    const bf16x8 B1H0 = mk_frag(h ? oph[2] : ph[0], h ? oph[3] : ph[1], h ? 0u : ph[4], 0u);
    const bf16x8 B1L0 = mk_frag(h ? opl[2] : pl[0], h ? opl[3] : pl[1], h ? 0u : pl[4], 0u);
    const bf16x8 B1H1 = mk_frag(h ? ph[2] : oph[0], h ? ph[3] : oph[1], h ? 0u : oph[4], 0u);
    const bf16x8 B1L1 = mk_frag(h ? pl[2] : opl[0], h ? pl[3] : opl[1], h ? 0u : opl[4], 0u);

    float w10t[2], w11t[2];

#pragma unroll
    for (int tI = 0; tI < 2; ++tI) {
        const bf16x8 B1H = tI ? B1H1 : B1H0;
        const bf16x8 B1L = tI ? B1L1 : B1L0;

        f32x16 c;
#pragma unroll
        for (int i = 0; i < 16; ++i) c[i] = 0.f;
        c = mfma32(A1H, B1H, c);
        c = mfma32(A1H, B1L, c);
        c = mfma32(A1L, B1H, c);
        c = mfma32(A1L, B1L, c);

        float h1v[16];
#pragma unroll
        for (int i = 0; i < 16; ++i) h1v[i] = silu_rcp(c[i] * INV_SQRT_NB);

        unsigned PH[8], PL[8];
#pragma unroll
        for (int i = 0; i < 8; ++i) {
            const float a0 = h1v[2 * i], b0 = h1v[2 * i + 1];
            PH[i] = pk_hi(a0, b0);
            PL[i] = pk_hi(a0 - trunc_hi(a0), b0 - trunc_hi(b0));
        }
        const bf16x8 B2H0 = mk_frag(PH[0], PH[1], PH[2], PH[3]);
        const bf16x8 B2L0 = mk_frag(PL[0], PL[1], PL[2], PL[3]);
        const bf16x8 B2H1 = mk_frag(PH[4], PH[5], PH[6], PH[7]);
        const bf16x8 B2L1 = mk_frag(PL[4], PL[5], PL[6], PL[7]);

        f32x16 c2;
#pragma unroll
        for (int i = 0; i < 16; ++i) c2[i] = 0.f;
        c2 = mfma32(A2H[0], B2H0, c2);
        c2 = mfma32(A2H[0], B2L0, c2);
        c2 = mfma32(A2L[0], B2H0, c2);
        c2 = mfma32(A2L[0], B2L0, c2);
        c2 = mfma32(A2H[1], B2H1, c2);
        c2 = mfma32(A2H[1], B2L1, c2);
        c2 = mfma32(A2L[1], B2H1, c2);
        c2 = mfma32(A2L[1], B2L1, c2);

        float pw0 = 0.f, pw1 = 0.f;
#pragma unroll
        for (int i = 0; i < 16; ++i) {
            const float h2i = silu_rcp(c2[i] * INV_SQRT_HID);
            pw0 = fmaf(h2i, w2a[i], pw0);
            pw1 = fmaf(h2i, w2b[i], pw1);
        }
        pw0 += __shfl_xor(pw0, 32, 64);
        pw1 += __shfl_xor(pw1, 32, 64);
        w10t[tI] = pw0;
        w11t[tI] = pw1;
    }

    const float w10 = (h ? w10t[1] : w10t[0]) * INV_SQRT_HID;
    const float w11 = (h ? w11t[1] : w11t[0]) * INV_SQRT_HID;

    const float xs = t[batch[src]] * lin1_w[0];
    float ms = w10 * xs * em;
    const float fv = w11 * xs * em;
    float mvx = fv * shx, mvy = fv * shy, mvz = fv * shz;

#pragma unroll
    for (int m = 16; m >= 1; m >>= 1) {
        ms  += __shfl_xor(ms,  m, 32);
        mvx += __shfl_xor(mvx, m, 32);
        mvy += __shfl_xor(mvy, m, 32);
        mvz += __shfl_xor(mvz, m, 32);
    }
    const float nms = ms  * INV_SQRT_K;
    const float nvx = mvx * INV_SQRT_K;
    const float nvy = mvy * INV_SQRT_K;
    const float nvz = mvz * INV_SQRT_K;

    // ---- node phase: lane owns hidden unit u of node n ----
    const float a  = t[batch[n]];
    const float hs = silu_div(C_S * a * sc1_w[u] + C_X * nms * a * l2s[u]);
    const float lv = l2v[u];
    const float hvx = silu_div(C_X * nvx * a * lv);
    const float hvy = silu_div(C_X * nvy * a * lv);
    const float hvz = silu_div(C_X * nvz * a * lv);

    const float s2 = sc2_w[u];
    float scx = hvx * s2, scy = hvy * s2, scz = hvz * s2;
#pragma unroll
    for (int m = 16; m >= 1; m >>= 1) {
        scx += __shfl_xor(scx, m, 32);
        scy += __shfl_xor(scy, m, 32);
        scz += __shfl_xor(scz, m, 32);
    }

    // folded node matvec: tab2[n][u] = (a/32) * Sum_v [hs|hv]·M_T[v][u]
    float tA = 0.f, tBx = 0.f, tBy = 0.f, tBz = 0.f;
    for (int v = 0; v < HIDc; ++v) {
        const float hsv = __shfl(hs,  v, 32);
        const float hx  = __shfl(hvx, v, 32);
        const float hy  = __shfl(hvy, v, 32);
        const float hz  = __shfl(hvz, v, 32);
        const float msw = MsT[v * 32 + u];
        const float mvw = MvT[v * 32 + u];
        tA  = fmaf(hsv, msw, tA);
        tBx = fmaf(hx, mvw, tBx);
        tBy = fmaf(hy, mvw, tBy);
        tBz = fmaf(hz, mvw, tBz);
    }
    const float sc_ = a * (1.0f / 32.0f);
    float4 t2;
    t2.x = tA  * sc_;
    t2.y = tBx * sc_;
    t2.z = tBy * sc_;
    t2.w = tBz * sc_;
    tab2[n * HIDc + u] = t2;

    if (u == 0) {
        const float s = C_S * a * INV_SQRT_HID;
        out_scpart[3 * n + 0] = scx * s;
        out_scpart[3 * n + 1] = scy * s;
        out_scpart[3 * n + 2] = scz * s;
    }
}

// ---------------------------------------------------------------------------
// Phase 2 — byte-identical to the R5/R6 version that passed.
// ---------------------------------------------------------------------------
__global__ __launch_bounds__(256) void se3_phase2(
    const float* __restrict__ coords, const float* __restrict__ t,
    const int* __restrict__ esrc, const float* __restrict__ emask,
    const float* __restrict__ W0, const float* __restrict__ W1,
    const float4* __restrict__ tab2, float* __restrict__ out)
{
    const int lane = threadIdx.x & 63;
    const int col  = lane & 31;
    const int h    = lane >> 5;

    float a1v[8];
#pragma unroll
    for (int e2 = 0; e2 < 8; ++e2) {
        const int k = (e2 & 3) + 8 * (e2 >> 2) + 4 * h;
        a1v[e2] = (k < NBc) ? W0[k * HIDc + col] : 0.f;
    }
    unsigned a1h_[4], a1l_[4];
#pragma unroll
    for (int j = 0; j < 4; ++j) {
        const float x = a1v[2 * j], y = a1v[2 * j + 1];
        a1h_[j] = pk_hi(x, y);
        a1l_[j] = pk_hi(x - trunc_hi(x), y - trunc_hi(y));
    }
    const bf16x8 A1H = mk_frag(a1h_[0], a1h_[1], a1h_[2], a1h_[3]);
    const bf16x8 A1L = mk_frag(a1l_[0], a1l_[1], a1l_[2], a1l_[3]);

    bf16x8 A2H[2], A2L[2];
#pragma unroll
    for (int ks = 0; ks < 2; ++ks) {
        float w[8];
#pragma unroll
        for (int e2 = 0; e2 < 8; ++e2) {
            const int k = 16 * ks + (e2 & 3) + 8 * (e2 >> 2) + 4 * h;
            w[e2] = W1[k * HIDc + col];
        }
        unsigned rh[4], rl[4];
#pragma unroll
        for (int j = 0; j < 4; ++j) {
            rh[j] = pk_hi(w[2 * j], w[2 * j + 1]);
            rl[j] = pk_hi(w[2 * j] - trunc_hi(w[2 * j]),
                          w[2 * j + 1] - trunc_hi(w[2 * j + 1]));
        }
        A2H[ks] = mk_frag(rh[0], rh[1], rh[2], rh[3]);
        A2L[ks] = mk_frag(rl[0], rl[1], rl[2], rl[3]);
    }

    const int wid = blockIdx.x * 4 + (threadIdx.x >> 6);
    const int e0  = wid * 64;
    const int g   = e0 + lane;
    const int nA  = e0 >> 5;
    const int myn = g >> 5;
    const int src = esrc[g];
    const float em = emask[g];

    const float dx = coords[3 * myn + 0] - coords[3 * src + 0];
    const float dy = coords[3 * myn + 1] - coords[3 * src + 1];
    const float dz = coords[3 * myn + 2] - coords[3 * src + 2];
    const float r  = sqrtf(dx * dx + dy * dy + dz * dz + 1e-12f);
    const float ir = 1.0f / r;
    const float shx = SQ3 * dx * ir, shy = SQ3 * dy * ir, shz = SQ3 * dz * ir;

    float embv[NBc];
#pragma unroll
    for (int b = 0; b < NBc; ++b) {
        const float d = r * INV_STEP - (float)b;
        embv[b] = __expf(-d * d) * EMB_SCALE;
    }

    unsigned ph[5], pl[5];
#pragma unroll
    for (int j = 0; j < 5; ++j) {
        const float a0 = embv[2 * j], b0 = embv[2 * j + 1];
        ph[j] = pk_hi(a0, b0);
        pl[j] = pk_hi(a0 - trunc_hi(a0), b0 - trunc_hi(b0));
    }
    unsigned oph[5], opl[5];
#pragma unroll
    for (int j = 0; j < 5; ++j) {
        oph[j] = __shfl_xor(ph[j], 32, 64);
        opl[j] = __shfl_xor(pl[j], 32, 64);
    }

    const bf16x8 B1H0 = mk_frag(h ? oph[2] : ph[0], h ? oph[3] : ph[1], h ? 0u : ph[4], 0u);
    const bf16x8 B1L0 = mk_frag(h ? opl[2] : pl[0], h ? opl[3] : pl[1], h ? 0u : pl[4], 0u);
    const bf16x8 B1H1 = mk_frag(h ? ph[2] : oph[0], h ? ph[3] : oph[1], h ? 0u : oph[4], 0u);
    const bf16x8 B1L1 = mk_frag(h ? pl[2] : opl[0], h ? pl[3] : opl[1], h ? 0u : opl[4], 0u);

    float cxo[2], cyo[2], czo[2];

#pragma unroll
    for (int tI = 0; tI < 2; ++tI) {
        const bf16x8 B1H = tI ? B1H1 : B1H0;
        const bf16x8 B1L = tI ? B1L1 : B1L0;

        f32x16 c;
#pragma unroll
        for (int i = 0; i < 16; ++i) c[i] = 0.f;
        c = mfma32(A1H, B1H, c);
        c = mfma32(A1H, B1L, c);
        c = mfma32(A1L, B1H, c);
        c = mfma32(A1L, B1L, c);

        float h1v[16];
#pragma unroll
        for (int i = 0; i < 16; ++i) h1v[i] = silu_rcp(c[i] * INV_SQRT_NB);

        unsigned PH[8], PL[8];
#pragma unroll
        for (int i = 0; i < 8; ++i) {
            const float a0 = h1v[2 * i], b0 = h1v[2 * i + 1];
            PH[i] = pk_hi(a0, b0);
            PL[i] = pk_hi(a0 - trunc_hi(a0), b0 - trunc_hi(b0));
        }
        const bf16x8 B2H0 = mk_frag(PH[0], PH[1], PH[2], PH[3]);
        const bf16x8 B2L0 = mk_frag(PL[0], PL[1], PL[2], PL[3]);
        const bf16x8 B2H1 = mk_frag(PH[4], PH[5], PH[6], PH[7]);
        const bf16x8 B2L1 = mk_frag(PL[4], PL[5], PL[6], PL[7]);

        f32x16 c2;
#pragma unroll
        for (int i = 0; i < 16; ++i) c2[i] = 0.f;
        c2 = mfma32(A2H[0], B2H0, c2);
        c2 = mfma32(A2H[0], B2L0, c2);
        c2 = mfma32(A2L[0], B2H0, c2);
        c2 = mfma32(A2L[0], B2L0, c2);
        c2 = mfma32(A2H[1], B2H1, c2);
        c2 = mfma32(A2H[1], B2L1, c2);
        c2 = mfma32(A2L[1], B2H1, c2);
        c2 = mfma32(A2L[1], B2L1, c2);

        float h2v[16];
#pragma unroll
        for (int i = 0; i < 16; ++i) h2v[i] = silu_rcp(c2[i] * INV_SQRT_HID);

        const int   srcT = __shfl(src, tI * 32 + col, 64);
        const float emT  = __shfl(em,  tI * 32 + col, 64);
        const float sxT  = __shfl(shx, tI * 32 + col, 64);
        const float syT  = __shfl(shy, tI * 32 + col, 64);
        const float szT  = __shfl(shz, tI * 32 + col, 64);

        const float4* __restrict__ tp = tab2 + srcT * HIDc;
        float pp = 0.f, qx = 0.f, qy = 0.f, qz = 0.f;
#pragma unroll
        for (int i = 0; i < 16; ++i) {
            const int u2 = (i & 3) + 8 * (i >> 2) + 4 * h;
            const float4 gq = tp[u2];
            pp = fmaf(h2v[i], gq.x, pp);
            qx = fmaf(h2v[i], gq.y, qx);
            qy = fmaf(h2v[i], gq.z, qy);
            qz = fmaf(h2v[i], gq.w, qz);
        }
        pp += __shfl_xor(pp, 32, 64);
        qx += __shfl_xor(qx, 32, 64);
        qy += __shfl_xor(qy, 32, 64);
        qz += __shfl_xor(qz, 32, 64);

        float cx = emT * fmaf(pp, sxT, qx);
        float cy = emT * fmaf(pp, syT, qy);
        float cz = emT * fmaf(pp, szT, qz);
#pragma unroll
        for (int m = 16; m >= 1; m >>= 1) {
            cx += __shfl_xor(cx, m, 64);
            cy += __shfl_xor(cy, m, 64);
            cz += __shfl_xor(cz, m, 64);
        }
        cxo[tI] = cx; cyo[tI] = cy; czo[tI] = cz;
    }

    if (lane < 2) {
        const int n = nA + lane;
        const float a = t[n >> 8];
        const float s = C_X * a * INV_SQRT_2HID * INV_SQRT_K;
        const float vx = lane ? cxo[1] : cxo[0];
        const float vy = lane ? cyo[1] : cyo[0];
        const float vz = lane ? czo[1] : czo[0];
        out[3 * n + 0] += vx * s;
        out[3 * n + 1] += vy * s;
        out[3 * n + 2] += vz * s;
    }
}

extern "C" void kernel_launch(void* const* d_in, const int* in_sizes, int n_in,
                              void* d_out, int out_size, void* d_ws, size_t ws_size,
                              hipStream_t stream) {
    const float* coords = (const float*)d_in[0];
    const float* t      = (const float*)d_in[1];
    const int*   batch  = (const int*)d_in[2];
    const int*   esrc   = (const int*)d_in[3];
    const float* emask  = (const float*)d_in[5];
    const float* sc1_w  = (const float*)d_in[6];
    const float* lin1_w = (const float*)d_in[7];
    const float* fc1_w0 = (const float*)d_in[8];
    const float* fc1_w1 = (const float*)d_in[9];
    const float* fc1_w2 = (const float*)d_in[10];
    const float* c1l2s  = (const float*)d_in[11];
    const float* c1l2v  = (const float*)d_in[12];
    const float* sc2_w  = (const float*)d_in[13];
    const float* lin1s  = (const float*)d_in[14];
    const float* lin1v  = (const float*)d_in[15];
    const float* fc2_w0 = (const float*)d_in[16];
    const float* fc2_w1 = (const float*)d_in[17];
    const float* fc2_w2 = (const float*)d_in[18];
    const float* c2a    = (const float*)d_in[19];
    const float* c2b    = (const float*)d_in[20];

    float*  out  = (float*)d_out;
    float4* tab2 = (float4*)d_ws;                       // 8 MB
    float*  MsT  = (float*)((char*)d_ws + (16384 * 32 * 16));  // after tab2
    float*  MvT  = MsT + 1024;

    const int nEdges = 16384 * Kc;         // 524288
    dim3 block(256);
    dim3 grid(nEdges / 256);               // 2048 blocks

    se3_pre<<<dim3(8), block, 0, stream>>>(lin1s, lin1v, fc2_w2, c2a, c2b, MsT, MvT);

    se3_phase1<<<grid, block, 0, stream>>>(coords, t, batch, esrc, emask,
        sc1_w, lin1_w, fc1_w0, fc1_w1, fc1_w2, c1l2s, c1l2v, sc2_w,
        MsT, MvT, tab2, out);

    se3_phase2<<<grid, block, 0, stream>>>(coords, t, esrc, emask,
        fc2_w0, fc2_w1, tab2, out);
}

// Round 8
// 148.261 us; speedup vs baseline: 1.4007x; 1.0071x over previous
//
#include <hip/hip_runtime.h>

namespace {
constexpr int Kc = 32, HIDc = 32, NBc = 10;
constexpr float C_S = 0.3826834323650898f;   // sin(pi/8)
constexpr float C_X = 0.9238795325112867f;   // cos(pi/8)
constexpr float SQ3 = 1.7320508075688772f;
constexpr float INV_SQRT_K   = 0.17677669529663687f;  // 1/sqrt(32)
constexpr float INV_SQRT_HID = 0.17677669529663687f;  // 1/sqrt(32)
constexpr float INV_SQRT_NB  = 0.31622776601683794f;  // 1/sqrt(10)
constexpr float INV_SQRT_2HID = 0.125f;               // 1/sqrt(64)
constexpr float INV_STEP  = 1.8f;                     // 1/(5/9)
constexpr float EMB_SCALE = 0.8928571428571429f;      // 1/1.12

typedef __attribute__((ext_vector_type(8)))  short bf16x8;
typedef __attribute__((ext_vector_type(16))) float f32x16;
typedef __attribute__((ext_vector_type(4)))  int   i32x4;

__device__ __forceinline__ float silu_rcp(float x) {
    return x * __builtin_amdgcn_rcpf(1.0f + __expf(-x));
}

// pack two f32 into one VGPR as 2 bf16 (truncation): low16=bf16(a), high16=bf16(b)
__device__ __forceinline__ unsigned pk_hi(float a, float b) {
    unsigned ua = __builtin_bit_cast(unsigned, a);
    unsigned ub = __builtin_bit_cast(unsigned, b);
    return (ua >> 16) | (ub & 0xFFFF0000u);
}
__device__ __forceinline__ float trunc_hi(float a) {
    return __builtin_bit_cast(float, __builtin_bit_cast(unsigned, a) & 0xFFFF0000u);
}
__device__ __forceinline__ bf16x8 mk_frag(unsigned r0, unsigned r1, unsigned r2, unsigned r3) {
    i32x4 t; t[0] = (int)r0; t[1] = (int)r1; t[2] = (int)r2; t[3] = (int)r3;
    return __builtin_bit_cast(bf16x8, t);
}
__device__ __forceinline__ f32x16 mfma32(bf16x8 a, bf16x8 b, f32x16 c) {
    return __builtin_amdgcn_mfma_f32_32x32x16_bf16(a, b, c, 0, 0, 0);
}
} // namespace

// ---------------------------------------------------------------------------
// Precompute (once per launch):
//   MsT[v*32+u] = Sum_j W2f2[u*64+j]    * c2a[j] * lin1s[v*32+j]
//   MvT[v*32+u] = Sum_j W2f2[u*64+32+j] * c2b[j] * lin1v[v*32+j]
// ---------------------------------------------------------------------------
__global__ __launch_bounds__(256) void se3_pre(
    const float* __restrict__ lin1s, const float* __restrict__ lin1v,
    const float* __restrict__ W2f2,
    const float* __restrict__ c2a, const float* __restrict__ c2b,
    float* __restrict__ MsT, float* __restrict__ MvT)
{
    const int id = blockIdx.x * 256 + threadIdx.x;   // 0..2047
    const int v = (id & 1023) >> 5;
    const int u = id & 31;
    float acc = 0.f;
    if (id < 1024) {
#pragma unroll
        for (int j = 0; j < 32; ++j)
            acc = fmaf(W2f2[u * 64 + j] * c2a[j], lin1s[v * 32 + j], acc);
        MsT[v * 32 + u] = acc;
    } else {
#pragma unroll
        for (int j = 0; j < 32; ++j)
            acc = fmaf(W2f2[u * 64 + 32 + j] * c2b[j], lin1v[v * 32 + j], acc);
        MvT[v * 32 + u] = acc;
    }
}

// ---------------------------------------------------------------------------
// Phase 1 (MFMA edge-MLP): wave = 2 nodes (64 edges).
// Node fold now uses per-wave LDS float4 broadcast (1 ds_write_b128/lane +
// 32 broadcast ds_read_b128) instead of 128 ds_bpermute. LL MFMAs dropped.
// ---------------------------------------------------------------------------
__global__ __launch_bounds__(256) void se3_phase1(
    const float* __restrict__ coords, const float* __restrict__ t,
    const int* __restrict__ batch, const int* __restrict__ esrc,
    const float* __restrict__ emask,
    const float* __restrict__ sc1_w, const float* __restrict__ lin1_w,
    const float* __restrict__ W0, const float* __restrict__ W1,
    const float* __restrict__ W2,
    const float* __restrict__ l2s, const float* __restrict__ l2v,
    const float* __restrict__ sc2_w,
    const float* __restrict__ MsT, const float* __restrict__ MvT,
    float4* __restrict__ tab2, float* __restrict__ out_scpart)
{
    __shared__ float4 Hsh[4][2][32];     // [wave][half(node)][unit] = 4 KB

    const int lane = threadIdx.x & 63;
    const int col  = lane & 31;
    const int h    = lane >> 5;
    const int widL = threadIdx.x >> 6;   // wave id within block

    // ---- A1 = W0^T (K=16, zero-padded beyond NB=10) ----
    float a1v[8];
#pragma unroll
    for (int e2 = 0; e2 < 8; ++e2) {
        const int k = (e2 & 3) + 8 * (e2 >> 2) + 4 * h;
        a1v[e2] = (k < NBc) ? W0[k * HIDc + col] : 0.f;
    }
    unsigned a1h_[4], a1l_[4];
#pragma unroll
    for (int j = 0; j < 4; ++j) {
        const float x = a1v[2 * j], y = a1v[2 * j + 1];
        a1h_[j] = pk_hi(x, y);
        a1l_[j] = pk_hi(x - trunc_hi(x), y - trunc_hi(y));
    }
    const bf16x8 A1H = mk_frag(a1h_[0], a1h_[1], a1h_[2], a1h_[3]);
    const bf16x8 A1L = mk_frag(a1l_[0], a1l_[1], a1l_[2], a1l_[3]);

    // ---- A2 = W1^T, K=32 as 2 K-steps of 16 ----
    bf16x8 A2H[2], A2L[2];
#pragma unroll
    for (int ks = 0; ks < 2; ++ks) {
        float w[8];
#pragma unroll
        for (int e2 = 0; e2 < 8; ++e2) {
            const int k = 16 * ks + (e2 & 3) + 8 * (e2 >> 2) + 4 * h;
            w[e2] = W1[k * HIDc + col];
        }
        unsigned rh[4], rl[4];
#pragma unroll
        for (int j = 0; j < 4; ++j) {
            rh[j] = pk_hi(w[2 * j], w[2 * j + 1]);
            rl[j] = pk_hi(w[2 * j] - trunc_hi(w[2 * j]),
                          w[2 * j + 1] - trunc_hi(w[2 * j + 1]));
        }
        A2H[ks] = mk_frag(rh[0], rh[1], rh[2], rh[3]);
        A2L[ks] = mk_frag(rl[0], rl[1], rl[2], rl[3]);
    }

    // ---- final-layer weights, 1/sqrt(HID) folded in (tI-invariant) ----
    float w2a[16], w2b[16];
#pragma unroll
    for (int i = 0; i < 16; ++i) {
        const int u2 = (i & 3) + 8 * (i >> 2) + 4 * h;
        w2a[i] = W2[2 * u2 + 0] * INV_SQRT_HID;
        w2b[i] = W2[2 * u2 + 1] * INV_SQRT_HID;
    }

    // ---- per-edge scalar work (lane owns edge g) ----
    const int wid = blockIdx.x * 4 + widL;
    const int e0  = wid * 64;
    const int g   = e0 + lane;
    const int n   = g >> 5;             // own node (half0 -> nA, half1 -> nA+1)
    const int u   = col;
    const int src = esrc[g];
    const float em = emask[g];

    const float dx = coords[3 * n + 0] - coords[3 * src + 0];
    const float dy = coords[3 * n + 1] - coords[3 * src + 1];
    const float dz = coords[3 * n + 2] - coords[3 * src + 2];
    const float r  = sqrtf(dx * dx + dy * dy + dz * dz + 1e-12f);
    const float ir = 1.0f / r;
    const float shx = SQ3 * dx * ir, shy = SQ3 * dy * ir, shz = SQ3 * dz * ir;

    float embv[NBc];
#pragma unroll
    for (int b = 0; b < NBc; ++b) {
        const float d = r * INV_STEP - (float)b;
        embv[b] = __expf(-d * d) * EMB_SCALE;
    }

    unsigned ph[5], pl[5];
#pragma unroll
    for (int j = 0; j < 5; ++j) {
        const float a0 = embv[2 * j], b0 = embv[2 * j + 1];
        ph[j] = pk_hi(a0, b0);
        pl[j] = pk_hi(a0 - trunc_hi(a0), b0 - trunc_hi(b0));
    }
    unsigned oph[5], opl[5];
#pragma unroll
    for (int j = 0; j < 5; ++j) {
        oph[j] = __shfl_xor(ph[j], 32, 64);
        opl[j] = __shfl_xor(pl[j], 32, 64);
    }

    const bf16x8 B1H0 = mk_frag(h ? oph[2] : ph[0], h ? oph[3] : ph[1], h ? 0u : ph[4], 0u);
    const bf16x8 B1L0 = mk_frag(h ? opl[2] : pl[0], h ? opl[3] : pl[1], h ? 0u : pl[4], 0u);
    const bf16x8 B1H1 = mk_frag(h ? ph[2] : oph[0], h ? ph[3] : oph[1], h ? 0u : oph[4], 0u);
    const bf16x8 B1L1 = mk_frag(h ? pl[2] : opl[0], h ? pl[3] : opl[1], h ? 0u : opl[4], 0u);

    float w10t[2], w11t[2];

#pragma unroll
    for (int tI = 0; tI < 2; ++tI) {
        const bf16x8 B1H = tI ? B1H1 : B1H0;
        const bf16x8 B1L = tI ? B1L1 : B1L0;

        f32x16 c;
#pragma unroll
        for (int i = 0; i < 16; ++i) c[i] = 0.f;
        c = mfma32(A1H, B1H, c);
        c = mfma32(A1H, B1L, c);
        c = mfma32(A1L, B1H, c);      // LL term dropped (<=2^-16 rel)

        float h1v[16];
#pragma unroll
        for (int i = 0; i < 16; ++i) h1v[i] = silu_rcp(c[i] * INV_SQRT_NB);

        unsigned PH[8], PL[8];
#pragma unroll
        for (int i = 0; i < 8; ++i) {
            const float a0 = h1v[2 * i], b0 = h1v[2 * i + 1];
            PH[i] = pk_hi(a0, b0);
            PL[i] = pk_hi(a0 - trunc_hi(a0), b0 - trunc_hi(b0));
        }
        const bf16x8 B2H0 = mk_frag(PH[0], PH[1], PH[2], PH[3]);
        const bf16x8 B2L0 = mk_frag(PL[0], PL[1], PL[2], PL[3]);
        const bf16x8 B2H1 = mk_frag(PH[4], PH[5], PH[6], PH[7]);
        const bf16x8 B2L1 = mk_frag(PL[4], PL[5], PL[6], PL[7]);

        f32x16 c2;
#pragma unroll
        for (int i = 0; i < 16; ++i) c2[i] = 0.f;
        c2 = mfma32(A2H[0], B2H0, c2);
        c2 = mfma32(A2H[0], B2L0, c2);
        c2 = mfma32(A2L[0], B2H0, c2);   // LL dropped
        c2 = mfma32(A2H[1], B2H1, c2);
        c2 = mfma32(A2H[1], B2L1, c2);
        c2 = mfma32(A2L[1], B2H1, c2);   // LL dropped

        float pw0 = 0.f, pw1 = 0.f;
#pragma unroll
        for (int i = 0; i < 16; ++i) {
            const float h2i = silu_rcp(c2[i] * INV_SQRT_HID);
            pw0 = fmaf(h2i, w2a[i], pw0);
            pw1 = fmaf(h2i, w2b[i], pw1);
        }
        pw0 += __shfl_xor(pw0, 32, 64);
        pw1 += __shfl_xor(pw1, 32, 64);
        w10t[tI] = pw0;
        w11t[tI] = pw1;
    }

    const float w10 = h ? w10t[1] : w10t[0];   // 1/sqrt(HID) already folded
    const float w11 = h ? w11t[1] : w11t[0];

    const float xs = t[batch[src]] * lin1_w[0];
    float ms = w10 * xs * em;
    const float fv = w11 * xs * em;
    float mvx = fv * shx, mvy = fv * shy, mvz = fv * shz;

#pragma unroll
    for (int m = 16; m >= 1; m >>= 1) {
        ms  += __shfl_xor(ms,  m, 32);
        mvx += __shfl_xor(mvx, m, 32);
        mvy += __shfl_xor(mvy, m, 32);
        mvz += __shfl_xor(mvz, m, 32);
    }
    const float nms = ms  * INV_SQRT_K;
    const float nvx = mvx * INV_SQRT_K;
    const float nvy = mvy * INV_SQRT_K;
    const float nvz = mvz * INV_SQRT_K;

    // ---- node phase: lane owns hidden unit u of node n ----
    const float a  = t[batch[n]];
    const float hs = silu_rcp(C_S * a * sc1_w[u] + C_X * nms * a * l2s[u]);
    const float lv = l2v[u];
    const float hvx = silu_rcp(C_X * nvx * a * lv);
    const float hvy = silu_rcp(C_X * nvy * a * lv);
    const float hvz = silu_rcp(C_X * nvz * a * lv);

    const float s2 = sc2_w[u];
    float scx = hvx * s2, scy = hvy * s2, scz = hvz * s2;
#pragma unroll
    for (int m = 16; m >= 1; m >>= 1) {
        scx += __shfl_xor(scx, m, 32);
        scy += __shfl_xor(scy, m, 32);
        scz += __shfl_xor(scz, m, 32);
    }

    // broadcast h-vectors via per-wave LDS (no barrier: same-wave prod/cons)
    Hsh[widL][h][u] = make_float4(hs, hvx, hvy, hvz);

    float tA = 0.f, tBx = 0.f, tBy = 0.f, tBz = 0.f;
    for (int v = 0; v < HIDc; ++v) {
        const float4 hv4 = Hsh[widL][h][v];     // broadcast read (uniform/half)
        const float msw = MsT[v * 32 + u];
        const float mvw = MvT[v * 32 + u];
        tA  = fmaf(hv4.x, msw, tA);
        tBx = fmaf(hv4.y, mvw, tBx);
        tBy = fmaf(hv4.z, mvw, tBy);
        tBz = fmaf(hv4.w, mvw, tBz);
    }
    const float sc_ = a * (1.0f / 32.0f);
    float4 t2;
    t2.x = tA  * sc_;
    t2.y = tBx * sc_;
    t2.z = tBy * sc_;
    t2.w = tBz * sc_;
    tab2[n * HIDc + u] = t2;

    if (u == 0) {
        const float s = C_S * a * INV_SQRT_HID;
        out_scpart[3 * n + 0] = scx * s;
        out_scpart[3 * n + 1] = scy * s;
        out_scpart[3 * n + 2] = scz * s;
    }
}

// ---------------------------------------------------------------------------
// Phase 2 — R5-verified structure, LL MFMAs dropped.
// ---------------------------------------------------------------------------
__global__ __launch_bounds__(256) void se3_phase2(
    const float* __restrict__ coords, const float* __restrict__ t,
    const int* __restrict__ esrc, const float* __restrict__ emask,
    const float* __restrict__ W0, const float* __restrict__ W1,
    const float4* __restrict__ tab2, float* __restrict__ out)
{
    const int lane = threadIdx.x & 63;
    const int col  = lane & 31;
    const int h    = lane >> 5;

    float a1v[8];
#pragma unroll
    for (int e2 = 0; e2 < 8; ++e2) {
        const int k = (e2 & 3) + 8 * (e2 >> 2) + 4 * h;
        a1v[e2] = (k < NBc) ? W0[k * HIDc + col] : 0.f;
    }
    unsigned a1h_[4], a1l_[4];
#pragma unroll
    for (int j = 0; j < 4; ++j) {
        const float x = a1v[2 * j], y = a1v[2 * j + 1];
        a1h_[j] = pk_hi(x, y);
        a1l_[j] = pk_hi(x - trunc_hi(x), y - trunc_hi(y));
    }
    const bf16x8 A1H = mk_frag(a1h_[0], a1h_[1], a1h_[2], a1h_[3]);
    const bf16x8 A1L = mk_frag(a1l_[0], a1l_[1], a1l_[2], a1l_[3]);

    bf16x8 A2H[2], A2L[2];
#pragma unroll
    for (int ks = 0; ks < 2; ++ks) {
        float w[8];
#pragma unroll
        for (int e2 = 0; e2 < 8; ++e2) {
            const int k = 16 * ks + (e2 & 3) + 8 * (e2 >> 2) + 4 * h;
            w[e2] = W1[k * HIDc + col];
        }
        unsigned rh[4], rl[4];
#pragma unroll
        for (int j = 0; j < 4; ++j) {
            rh[j] = pk_hi(w[2 * j], w[2 * j + 1]);
            rl[j] = pk_hi(w[2 * j] - trunc_hi(w[2 * j]),
                          w[2 * j + 1] - trunc_hi(w[2 * j + 1]));
        }
        A2H[ks] = mk_frag(rh[0], rh[1], rh[2], rh[3]);
        A2L[ks] = mk_frag(rl[0], rl[1], rl[2], rl[3]);
    }

    const int wid = blockIdx.x * 4 + (threadIdx.x >> 6);
    const int e0  = wid * 64;
    const int g   = e0 + lane;
    const int nA  = e0 >> 5;
    const int myn = g >> 5;
    const int src = esrc[g];
    const float em = emask[g];

    const float dx = coords[3 * myn + 0] - coords[3 * src + 0];
    const float dy = coords[3 * myn + 1] - coords[3 * src + 1];
    const float dz = coords[3 * myn + 2] - coords[3 * src + 2];
    const float r  = sqrtf(dx * dx + dy * dy + dz * dz + 1e-12f);
    const float ir = 1.0f / r;
    const float shx = SQ3 * dx * ir, shy = SQ3 * dy * ir, shz = SQ3 * dz * ir;

    float embv[NBc];
#pragma unroll
    for (int b = 0; b < NBc; ++b) {
        const float d = r * INV_STEP - (float)b;
        embv[b] = __expf(-d * d) * EMB_SCALE;
    }

    unsigned ph[5], pl[5];
#pragma unroll
    for (int j = 0; j < 5; ++j) {
        const float a0 = embv[2 * j], b0 = embv[2 * j + 1];
        ph[j] = pk_hi(a0, b0);
        pl[j] = pk_hi(a0 - trunc_hi(a0), b0 - trunc_hi(b0));
    }
    unsigned oph[5], opl[5];
#pragma unroll
    for (int j = 0; j < 5; ++j) {
        oph[j] = __shfl_xor(ph[j], 32, 64);
        opl[j] = __shfl_xor(pl[j], 32, 64);
    }

    const bf16x8 B1H0 = mk_frag(h ? oph[2] : ph[0], h ? oph[3] : ph[1], h ? 0u : ph[4], 0u);
    const bf16x8 B1L0 = mk_frag(h ? opl[2] : pl[0], h ? opl[3] : pl[1], h ? 0u : pl[4], 0u);
    const bf16x8 B1H1 = mk_frag(h ? ph[2] : oph[0], h ? ph[3] : oph[1], h ? 0u : oph[4], 0u);
    const bf16x8 B1L1 = mk_frag(h ? pl[2] : opl[0], h ? pl[3] : opl[1], h ? 0u : opl[4], 0u);

    float cxo[2], cyo[2], czo[2];

#pragma unroll
    for (int tI = 0; tI < 2; ++tI) {
        const bf16x8 B1H = tI ? B1H1 : B1H0;
        const bf16x8 B1L = tI ? B1L1 : B1L0;

        f32x16 c;
#pragma unroll
        for (int i = 0; i < 16; ++i) c[i] = 0.f;
        c = mfma32(A1H, B1H, c);
        c = mfma32(A1H, B1L, c);
        c = mfma32(A1L, B1H, c);      // LL dropped

        float h1v[16];
#pragma unroll
        for (int i = 0; i < 16; ++i) h1v[i] = silu_rcp(c[i] * INV_SQRT_NB);

        unsigned PH[8], PL[8];
#pragma unroll
        for (int i = 0; i < 8; ++i) {
            const float a0 = h1v[2 * i], b0 = h1v[2 * i + 1];
            PH[i] = pk_hi(a0, b0);
            PL[i] = pk_hi(a0 - trunc_hi(a0), b0 - trunc_hi(b0));
        }
        const bf16x8 B2H0 = mk_frag(PH[0], PH[1], PH[2], PH[3]);
        const bf16x8 B2L0 = mk_frag(PL[0], PL[1], PL[2], PL[3]);
        const bf16x8 B2H1 = mk_frag(PH[4], PH[5], PH[6], PH[7]);
        const bf16x8 B2L1 = mk_frag(PL[4], PL[5], PL[6], PL[7]);

        f32x16 c2;
#pragma unroll
        for (int i = 0; i < 16; ++i) c2[i] = 0.f;
        c2 = mfma32(A2H[0], B2H0, c2);
        c2 = mfma32(A2H[0], B2L0, c2);
        c2 = mfma32(A2L[0], B2H0, c2);   // LL dropped
        c2 = mfma32(A2H[1], B2H1, c2);
        c2 = mfma32(A2H[1], B2L1, c2);
        c2 = mfma32(A2L[1], B2H1, c2);   // LL dropped

        float h2v[16];
#pragma unroll
        for (int i = 0; i < 16; ++i) h2v[i] = silu_rcp(c2[i] * INV_SQRT_HID);

        const int   srcT = __shfl(src, tI * 32 + col, 64);
        const float emT  = __shfl(em,  tI * 32 + col, 64);
        const float sxT  = __shfl(shx, tI * 32 + col, 64);
        const float syT  = __shfl(shy, tI * 32 + col, 64);
        const float szT  = __shfl(shz, tI * 32 + col, 64);

        const float4* __restrict__ tp = tab2 + srcT * HIDc;
        float pp = 0.f, qx = 0.f, qy = 0.f, qz = 0.f;
#pragma unroll
        for (int i = 0; i < 16; ++i) {
            const int u2 = (i & 3) + 8 * (i >> 2) + 4 * h;
            const float4 gq = tp[u2];
            pp = fmaf(h2v[i], gq.x, pp);
            qx = fmaf(h2v[i], gq.y, qx);
            qy = fmaf(h2v[i], gq.z, qy);
            qz = fmaf(h2v[i], gq.w, qz);
        }
        pp += __shfl_xor(pp, 32, 64);
        qx += __shfl_xor(qx, 32, 64);
        qy += __shfl_xor(qy, 32, 64);
        qz += __shfl_xor(qz, 32, 64);

        float cx = emT * fmaf(pp, sxT, qx);
        float cy = emT * fmaf(pp, syT, qy);
        float cz = emT * fmaf(pp, szT, qz);
#pragma unroll
        for (int m = 16; m >= 1; m >>= 1) {
            cx += __shfl_xor(cx, m, 64);
            cy += __shfl_xor(cy, m, 64);
            cz += __shfl_xor(cz, m, 64);
        }
        cxo[tI] = cx; cyo[tI] = cy; czo[tI] = cz;
    }

    if (lane < 2) {
        const int n = nA + lane;
        const float a = t[n >> 8];
        const float s = C_X * a * INV_SQRT_2HID * INV_SQRT_K;
        const float vx = lane ? cxo[1] : cxo[0];
        const float vy = lane ? cyo[1] : cyo[0];
        const float vz = lane ? czo[1] : czo[0];
        out[3 * n + 0] += vx * s;
        out[3 * n + 1] += vy * s;
        out[3 * n + 2] += vz * s;
    }
}

extern "C" void kernel_launch(void* const* d_in, const int* in_sizes, int n_in,
                              void* d_out, int out_size, void* d_ws, size_t ws_size,
                              hipStream_t stream) {
    const float* coords = (const float*)d_in[0];
    const float* t      = (const float*)d_in[1];
    const int*   batch  = (const int*)d_in[2];
    const int*   esrc   = (const int*)d_in[3];
    const float* emask  = (const float*)d_in[5];
    const float* sc1_w  = (const float*)d_in[6];
    const float* lin1_w = (const float*)d_in[7];
    const float* fc1_w0 = (const float*)d_in[8];
    const float* fc1_w1 = (const float*)d_in[9];
    const float* fc1_w2 = (const float*)d_in[10];
    const float* c1l2s  = (const float*)d_in[11];
    const float* c1l2v  = (const float*)d_in[12];
    const float* sc2_w  = (const float*)d_in[13];
    const float* lin1s  = (const float*)d_in[14];
    const float* lin1v  = (const float*)d_in[15];
    const float* fc2_w0 = (const float*)d_in[16];
    const float* fc2_w1 = (const float*)d_in[17];
    const float* fc2_w2 = (const float*)d_in[18];
    const float* c2a    = (const float*)d_in[19];
    const float* c2b    = (const float*)d_in[20];

    float*  out  = (float*)d_out;
    float4* tab2 = (float4*)d_ws;                              // 8 MB
    float*  MsT  = (float*)((char*)d_ws + (16384 * 32 * 16));  // after tab2
    float*  MvT  = MsT + 1024;

    const int nEdges = 16384 * Kc;         // 524288
    dim3 block(256);
    dim3 grid(nEdges / 256);               // 2048 blocks

    se3_pre<<<dim3(8), block, 0, stream>>>(lin1s, lin1v, fc2_w2, c2a, c2b, MsT, MvT);

    se3_phase1<<<grid, block, 0, stream>>>(coords, t, batch, esrc, emask,
        sc1_w, lin1_w, fc1_w0, fc1_w1, fc1_w2, c1l2s, c1l2v, sc2_w,
        MsT, MvT, tab2, out);

    se3_phase2<<<grid, block, 0, stream>>>(coords, t, esrc, emask,
        fc2_w0, fc2_w1, tab2, out);
}

// Round 9
// 134.000 us; speedup vs baseline: 1.5498x; 1.1064x over previous
//
#include <hip/hip_runtime.h>

namespace {
constexpr int Kc = 32, HIDc = 32, NBc = 10;
constexpr float C_S = 0.3826834323650898f;   // sin(pi/8)
constexpr float C_X = 0.9238795325112867f;   // cos(pi/8)
constexpr float SQ3 = 1.7320508075688772f;
constexpr float INV_SQRT_K   = 0.17677669529663687f;  // 1/sqrt(32)
constexpr float INV_SQRT_HID = 0.17677669529663687f;  // 1/sqrt(32)
constexpr float INV_SQRT_NB  = 0.31622776601683794f;  // 1/sqrt(10)
constexpr float INV_SQRT_2HID = 0.125f;               // 1/sqrt(64)
constexpr float INV_STEP  = 1.8f;                     // 1/(5/9)
constexpr float EMB_SCALE = 0.8928571428571429f;      // 1/1.12

constexpr int   TABN   = 2048;
constexpr float TSCALE = 2047.0f / 5.0f;             // index scale over [0,5]

__device__ __forceinline__ float silu_div(float x) {
    return x / (1.0f + __expf(-x));
}
__device__ __forceinline__ float silu_rcp(float x) {
    return x * __builtin_amdgcn_rcpf(1.0f + __expf(-x));
}
} // namespace

// ---------------------------------------------------------------------------
// Build kernel (one launch, 264 blocks):
//  blocks 0..255 : radial tables. Row i (r_i = 5*i/2047), 32 lanes per row:
//     w1tab[i][0..1] = _radial_fc1(emb(r_i))            (exact f32 MLP)
//     w2tab[i][0..31] = h2_fc2(r_i) = silu((silu(emb@W0/sN)@W1)/sH)
//  blocks 256..263: MsT/MvT fold matrices (as R7/R8 pre):
//     MsT[v*32+u] = Sum_j W2f2[u*64+j]   *c2a[j]*lin1s[v*32+j]
//     MvT[v*32+u] = Sum_j W2f2[u*64+32+j]*c2b[j]*lin1v[v*32+j]
// ---------------------------------------------------------------------------
__global__ __launch_bounds__(256) void se3_build(
    const float* __restrict__ f1w0, const float* __restrict__ f1w1,
    const float* __restrict__ f1w2,
    const float* __restrict__ f2w0, const float* __restrict__ f2w1,
    const float* __restrict__ lin1s, const float* __restrict__ lin1v,
    const float* __restrict__ W2f2,
    const float* __restrict__ c2a, const float* __restrict__ c2b,
    float* __restrict__ w1tab, float* __restrict__ w2tab,
    float* __restrict__ MsT, float* __restrict__ MvT)
{
    if (blockIdx.x < 256) {
        const int gid = blockIdx.x * 256 + threadIdx.x;
        const int i = gid >> 5;
        const int u = gid & 31;
        const float r = (float)i * (5.0f / 2047.0f);

        float emb[NBc];
#pragma unroll
        for (int b = 0; b < NBc; ++b) {
            const float d = r * INV_STEP - (float)b;
            emb[b] = __expf(-d * d) * EMB_SCALE;
        }

        // fc1 chain -> w1 pair
        float acc = 0.f;
#pragma unroll
        for (int b = 0; b < NBc; ++b) acc = fmaf(emb[b], f1w0[b * HIDc + u], acc);
        const float h1a = silu_div(acc * INV_SQRT_NB);
        acc = 0.f;
        for (int v = 0; v < HIDc; ++v)
            acc = fmaf(__shfl(h1a, v, 32), f1w1[v * HIDc + u], acc);
        const float h2a = silu_div(acc * INV_SQRT_HID);
        float wa = 0.f, wb = 0.f;
        for (int v = 0; v < HIDc; ++v) {
            const float hv = __shfl(h2a, v, 32);
            wa = fmaf(hv, f1w2[2 * v + 0], wa);
            wb = fmaf(hv, f1w2[2 * v + 1], wb);
        }
        if (u == 0) {
            w1tab[2 * i + 0] = wa * INV_SQRT_HID;
            w1tab[2 * i + 1] = wb * INV_SQRT_HID;
        }

        // fc2 chain -> h2 row
        acc = 0.f;
#pragma unroll
        for (int b = 0; b < NBc; ++b) acc = fmaf(emb[b], f2w0[b * HIDc + u], acc);
        const float g1 = silu_div(acc * INV_SQRT_NB);
        acc = 0.f;
        for (int v = 0; v < HIDc; ++v)
            acc = fmaf(__shfl(g1, v, 32), f2w1[v * HIDc + u], acc);
        w2tab[i * HIDc + u] = silu_div(acc * INV_SQRT_HID);
    } else {
        const int id = (blockIdx.x - 256) * 256 + threadIdx.x;   // 0..2047
        const int v = (id & 1023) >> 5;
        const int u = id & 31;
        float acc = 0.f;
        if (id < 1024) {
#pragma unroll
            for (int j = 0; j < 32; ++j)
                acc = fmaf(W2f2[u * 64 + j] * c2a[j], lin1s[v * 32 + j], acc);
            MsT[v * 32 + u] = acc;
        } else {
#pragma unroll
            for (int j = 0; j < 32; ++j)
                acc = fmaf(W2f2[u * 64 + 32 + j] * c2b[j], lin1v[v * 32 + j], acc);
            MvT[v * 32 + u] = acc;
        }
    }
}

// ---------------------------------------------------------------------------
// Phase 1: per edge, w1 via table lerp -> butterfly segment sums ->
// node phase (R8-verified: Hsh broadcast + MsT/MvT fold) -> tab2, sc_v out.
// ---------------------------------------------------------------------------
__global__ __launch_bounds__(256) void se3_phase1(
    const float* __restrict__ coords, const float* __restrict__ t,
    const int* __restrict__ batch, const int* __restrict__ esrc,
    const float* __restrict__ emask,
    const float* __restrict__ sc1_w, const float* __restrict__ lin1_w,
    const float* __restrict__ l2s, const float* __restrict__ l2v,
    const float* __restrict__ sc2_w,
    const float* __restrict__ w1tab,
    const float* __restrict__ MsT, const float* __restrict__ MvT,
    float4* __restrict__ tab2, float* __restrict__ out_scpart)
{
    __shared__ float4 Hsh[4][2][32];     // [wave][half(node)][unit]

    const int e    = blockIdx.x * 256 + threadIdx.x;
    const int n    = e >> 5;
    const int u    = threadIdx.x & 31;
    const int h    = (threadIdx.x >> 5) & 1;
    const int widL = threadIdx.x >> 6;
    const int src  = esrc[e];
    const float em = emask[e];

    const float dx = coords[3 * n + 0] - coords[3 * src + 0];
    const float dy = coords[3 * n + 1] - coords[3 * src + 1];
    const float dz = coords[3 * n + 2] - coords[3 * src + 2];
    const float r  = sqrtf(dx * dx + dy * dy + dz * dz + 1e-12f);
    const float ir = 1.0f / r;
    const float shx = SQ3 * dx * ir, shy = SQ3 * dy * ir, shz = SQ3 * dz * ir;

    // w1 via table (valid edges have r < 5; masked edges clamped, em=0 kills them)
    const float x = fminf(r, 5.0f) * TSCALE;
    int i0 = (int)x; i0 = (i0 > TABN - 2) ? (TABN - 2) : i0;
    const float f = x - (float)i0;
    const float wA0 = w1tab[2 * i0 + 0], wA1 = w1tab[2 * i0 + 2];
    const float wB0 = w1tab[2 * i0 + 1], wB1 = w1tab[2 * i0 + 3];
    const float w10 = fmaf(f, wA1 - wA0, wA0);   // 1/sqrt(HID) already folded
    const float w11 = fmaf(f, wB1 - wB0, wB0);

    const float xs = t[batch[src]] * lin1_w[0];
    float ms = w10 * xs * em;
    const float fv = w11 * xs * em;
    float mvx = fv * shx, mvy = fv * shy, mvz = fv * shz;

#pragma unroll
    for (int m = 16; m >= 1; m >>= 1) {
        ms  += __shfl_xor(ms,  m, 32);
        mvx += __shfl_xor(mvx, m, 32);
        mvy += __shfl_xor(mvy, m, 32);
        mvz += __shfl_xor(mvz, m, 32);
    }
    const float nms = ms  * INV_SQRT_K;
    const float nvx = mvx * INV_SQRT_K;
    const float nvy = mvy * INV_SQRT_K;
    const float nvz = mvz * INV_SQRT_K;

    // ---- node phase (R8-verified): lane owns hidden unit u of node n ----
    const float a  = t[batch[n]];
    const float hs = silu_rcp(C_S * a * sc1_w[u] + C_X * nms * a * l2s[u]);
    const float lv = l2v[u];
    const float hvx = silu_rcp(C_X * nvx * a * lv);
    const float hvy = silu_rcp(C_X * nvy * a * lv);
    const float hvz = silu_rcp(C_X * nvz * a * lv);

    const float s2 = sc2_w[u];
    float scx = hvx * s2, scy = hvy * s2, scz = hvz * s2;
#pragma unroll
    for (int m = 16; m >= 1; m >>= 1) {
        scx += __shfl_xor(scx, m, 32);
        scy += __shfl_xor(scy, m, 32);
        scz += __shfl_xor(scz, m, 32);
    }

    Hsh[widL][h][u] = make_float4(hs, hvx, hvy, hvz);

    float tA = 0.f, tBx = 0.f, tBy = 0.f, tBz = 0.f;
    for (int v = 0; v < HIDc; ++v) {
        const float4 hv4 = Hsh[widL][h][v];
        const float msw = MsT[v * 32 + u];
        const float mvw = MvT[v * 32 + u];
        tA  = fmaf(hv4.x, msw, tA);
        tBx = fmaf(hv4.y, mvw, tBx);
        tBy = fmaf(hv4.z, mvw, tBy);
        tBz = fmaf(hv4.w, mvw, tBz);
    }
    const float sc_ = a * (1.0f / 32.0f);
    float4 t2;
    t2.x = tA  * sc_;
    t2.y = tBx * sc_;
    t2.z = tBy * sc_;
    t2.w = tBz * sc_;
    tab2[n * HIDc + u] = t2;

    if (u == 0) {
        const float s = C_S * a * INV_SQRT_HID;
        out_scpart[3 * n + 0] = scx * s;
        out_scpart[3 * n + 1] = scy * s;
        out_scpart[3 * n + 2] = scz * s;
    }
}

// ---------------------------------------------------------------------------
// Phase 2: per edge, h2_fc2 via table lerp, p/q = dot with tab2[src],
// width-32 butterfly, lane0 RMW into out. Gather skipped when em==0.
// ---------------------------------------------------------------------------
__global__ __launch_bounds__(256) void se3_phase2(
    const float* __restrict__ coords, const float* __restrict__ t,
    const int* __restrict__ esrc, const float* __restrict__ emask,
    const float* __restrict__ w2tab,
    const float4* __restrict__ tab2, float* __restrict__ out)
{
    const int e    = blockIdx.x * 256 + threadIdx.x;
    const int n    = e >> 5;
    const int u    = threadIdx.x & 31;
    const int src  = esrc[e];
    const float em = emask[e];

    const float dx = coords[3 * n + 0] - coords[3 * src + 0];
    const float dy = coords[3 * n + 1] - coords[3 * src + 1];
    const float dz = coords[3 * n + 2] - coords[3 * src + 2];
    const float r  = sqrtf(dx * dx + dy * dy + dz * dz + 1e-12f);
    const float ir = 1.0f / r;
    const float shx = SQ3 * dx * ir, shy = SQ3 * dy * ir, shz = SQ3 * dz * ir;

    float p = 0.f, qx = 0.f, qy = 0.f, qz = 0.f;
    if (em != 0.0f) {
        const float x = fminf(r, 5.0f) * TSCALE;
        int i0 = (int)x; i0 = (i0 > TABN - 2) ? (TABN - 2) : i0;
        const float f = x - (float)i0;
        const float4* __restrict__ ra = (const float4*)(w2tab + i0 * HIDc);
        const float4* __restrict__ rb = ra + 8;
        const float4* __restrict__ tp = tab2 + src * HIDc;
#pragma unroll
        for (int q = 0; q < 8; ++q) {
            const float4 h0 = ra[q];
            const float4 h1 = rb[q];
            const float hx0 = fmaf(f, h1.x - h0.x, h0.x);
            const float hx1 = fmaf(f, h1.y - h0.y, h0.y);
            const float hx2 = fmaf(f, h1.z - h0.z, h0.z);
            const float hx3 = fmaf(f, h1.w - h0.w, h0.w);
            const float4 g0 = tp[4 * q + 0];
            const float4 g1 = tp[4 * q + 1];
            const float4 g2 = tp[4 * q + 2];
            const float4 g3 = tp[4 * q + 3];
            p  = fmaf(hx0, g0.x, p);  qx = fmaf(hx0, g0.y, qx);
            qy = fmaf(hx0, g0.z, qy); qz = fmaf(hx0, g0.w, qz);
            p  = fmaf(hx1, g1.x, p);  qx = fmaf(hx1, g1.y, qx);
            qy = fmaf(hx1, g1.z, qy); qz = fmaf(hx1, g1.w, qz);
            p  = fmaf(hx2, g2.x, p);  qx = fmaf(hx2, g2.y, qx);
            qy = fmaf(hx2, g2.z, qy); qz = fmaf(hx2, g2.w, qz);
            p  = fmaf(hx3, g3.x, p);  qx = fmaf(hx3, g3.y, qx);
            qy = fmaf(hx3, g3.z, qy); qz = fmaf(hx3, g3.w, qz);
        }
    }

    float cx = em * fmaf(p, shx, qx);
    float cy = em * fmaf(p, shy, qy);
    float cz = em * fmaf(p, shz, qz);
#pragma unroll
    for (int m = 16; m >= 1; m >>= 1) {
        cx += __shfl_xor(cx, m, 32);
        cy += __shfl_xor(cy, m, 32);
        cz += __shfl_xor(cz, m, 32);
    }

    if (u == 0) {
        const float a = t[n >> 8];
        const float s = C_X * a * INV_SQRT_2HID * INV_SQRT_K;
        out[3 * n + 0] = out[3 * n + 0] + cx * s;
        out[3 * n + 1] = out[3 * n + 1] + cy * s;
        out[3 * n + 2] = out[3 * n + 2] + cz * s;
    }
}

extern "C" void kernel_launch(void* const* d_in, const int* in_sizes, int n_in,
                              void* d_out, int out_size, void* d_ws, size_t ws_size,
                              hipStream_t stream) {
    const float* coords = (const float*)d_in[0];
    const float* t      = (const float*)d_in[1];
    const int*   batch  = (const int*)d_in[2];
    const int*   esrc   = (const int*)d_in[3];
    const float* emask  = (const float*)d_in[5];
    const float* sc1_w  = (const float*)d_in[6];
    const float* lin1_w = (const float*)d_in[7];
    const float* fc1_w0 = (const float*)d_in[8];
    const float* fc1_w1 = (const float*)d_in[9];
    const float* fc1_w2 = (const float*)d_in[10];
    const float* c1l2s  = (const float*)d_in[11];
    const float* c1l2v  = (const float*)d_in[12];
    const float* sc2_w  = (const float*)d_in[13];
    const float* lin1s  = (const float*)d_in[14];
    const float* lin1v  = (const float*)d_in[15];
    const float* fc2_w0 = (const float*)d_in[16];
    const float* fc2_w1 = (const float*)d_in[17];
    const float* fc2_w2 = (const float*)d_in[18];
    const float* c2a    = (const float*)d_in[19];
    const float* c2b    = (const float*)d_in[20];

    float*  out  = (float*)d_out;
    float4* tab2 = (float4*)d_ws;                         // 8 MB
    float*  aux  = (float*)((char*)d_ws + 16384 * 32 * 16);
    float*  MsT   = aux;                                  // 1024 f
    float*  MvT   = aux + 1024;                           // 1024 f
    float*  w1tab = aux + 2048;                           // 4096 f
    float*  w2tab = aux + 6144;                           // 65536 f

    const int nEdges = 16384 * Kc;         // 524288
    dim3 block(256);
    dim3 grid(nEdges / 256);               // 2048 blocks

    se3_build<<<dim3(264), block, 0, stream>>>(
        fc1_w0, fc1_w1, fc1_w2, fc2_w0, fc2_w1,
        lin1s, lin1v, fc2_w2, c2a, c2b, w1tab, w2tab, MsT, MvT);

    se3_phase1<<<grid, block, 0, stream>>>(coords, t, batch, esrc, emask,
        sc1_w, lin1_w, c1l2s, c1l2v, sc2_w, w1tab, MsT, MvT, tab2, out);

    se3_phase2<<<grid, block, 0, stream>>>(coords, t, esrc, emask,
        w2tab, tab2, out);
}